// Round 2
// baseline (5614.699 us; speedup 1.0000x reference)
//
#include <hip/hip_runtime.h>
#include <hip/hip_bf16.h>
#include <math.h>

// ============================================================================
// DoubleJpeg round 1: same pipeline as round 0 but bf16 storage for all conv
// intermediates so the workspace fits in ~126 MB (round 0 assumed 279 MB and
// most likely overflowed ws_size -> GPU fault -> core dump).
// Arena A (62.91 MB): xd(fp32) -> A(pre1a bf16) -> P1 -> P2 -> inT
// Arena B (62.91 MB): feat(fp32) -> B(pre1b bf16) -> C2 -> D3
// Small: in2T/in3T/z1pre fp32 + BN stats.
// ============================================================================

typedef __hip_bfloat16 bf16;

#define GAMMA_F 1.0e6f

__device__ __forceinline__ float cvt(float v) { return v; }
__device__ __forceinline__ float cvt(bf16 v) { return __bfloat162float(v); }
__device__ __forceinline__ void stv(float* p, float v) { *p = v; }
__device__ __forceinline__ void stv(bf16* p, float v) { *p = __float2bfloat16(v); }

// ---------------------------------------------------------------- DCT kernel
// grid (B*8) x 256 threads; each wave handles one block-row of 32 8x8 blocks.
__global__ __launch_bounds__(256) void k_dct(const float* __restrict__ x,
                                             const float* __restrict__ basis,
                                             float* __restrict__ xd) {
  __shared__ float bT[4096];     // bT[p*64+k] = basis[k*64+p]
  __shared__ float pix[4][64];
  int tid = threadIdx.x;
  for (int e = tid; e < 4096; e += 256)
    bT[e] = basis[(e & 63) * 64 + (e >> 6)];
  __syncthreads();
  int w = tid >> 6, lane = tid & 63;
  int b = blockIdx.x >> 3;
  int br = ((blockIdx.x & 7) << 2) + w;          // block-row 0..31
  const float* xb = x + (size_t)b * 65536;
  float* xdb = xd + (size_t)b * 65536;           // 64 coef * 1024 spatial
  for (int bc = 0; bc < 32; ++bc) {
    __syncthreads();
    pix[w][lane] = xb[(br * 8 + (lane >> 3)) * 256 + bc * 8 + (lane & 7)];
    __syncthreads();
    float acc = 0.f;
#pragma unroll
    for (int p = 0; p < 64; ++p)
      acc = fmaf(bT[p * 64 + lane], pix[w][p], acc);
    xdb[lane * 1024 + br * 32 + bc] = acc;
  }
}

// ---------------------------------------------------- soft histogram -> feat
// grid 4096 (= b*64+c) x 256. feat[b][j][c], j in [0,120).
__global__ __launch_bounds__(256) void k_hist(const float* __restrict__ xd,
                                              float* __restrict__ feat) {
  __shared__ float bins[120];
  int tid = threadIdx.x;
  int bc = blockIdx.x;
  int b = bc >> 6, c = bc & 63;
  if (tid < 120) bins[tid] = 0.f;
  __syncthreads();
  const float* p = xd + (size_t)bc * 1024;
#pragma unroll
  for (int k = 0; k < 4; ++k) {
    float v = p[tid + k * 256];
    float fl = floorf(v);
    float u = v - fl;                       // in [0,1)
    float sa = 1.f / (1.f + expf(-GAMMA_F * u));          // == 1 unless u tiny
    float sb = 1.f / (1.f + expf(-GAMMA_F * (u - 1.f)));  // == 0 unless u~1
    int j = (int)fl + 60;
    if ((unsigned)j < 120u) atomicAdd(&bins[j], sa - sb);
    if (sa < 1.f && (unsigned)(j - 1) < 120u) atomicAdd(&bins[j - 1], 1.f - sa);
    if (sb > 0.f && (unsigned)(j + 1) < 120u) atomicAdd(&bins[j + 1], sb);
  }
  __syncthreads();
  if (tid < 120) feat[((size_t)b * 120 + tid) * 64 + c] = bins[tid] * (1.f / 1024.f);
}

// --------------------------------------------------------- direct 5x5 conv
// block 256 (16x16 spatial), 8 output channels per thread.
// grid: (tilesW*tilesH, B, Cout/8). Weight indices wave-uniform -> s_loads.
template <int CIN, int H, int W, typename IT, typename OT>
__global__ __launch_bounds__(256) void k_conv5(const IT* __restrict__ in,
                                               const float* __restrict__ wgt,
                                               const float* __restrict__ bias,
                                               OT* __restrict__ out, int Cout) {
  constexpr int TW = (W + 15) / 16;
  __shared__ float tile[20 * 21];
  int tx = threadIdx.x & 15, ty = threadIdx.x >> 4;
  int tileX = (blockIdx.x % TW) * 16, tileY = (blockIdx.x / TW) * 16;
  int b = blockIdx.y, ocb = blockIdx.z * 8;
  float acc[8];
#pragma unroll
  for (int o = 0; o < 8; ++o) acc[o] = 0.f;

  for (int c = 0; c < CIN; ++c) {
    const IT* inc = in + ((size_t)(b * CIN + c) * H) * W;
    __syncthreads();
    for (int e = threadIdx.x; e < 400; e += 256) {
      int ly = e / 20, lx = e % 20;
      int gy = tileY - 2 + ly, gx = tileX - 2 + lx;
      float v = 0.f;
      if ((unsigned)gy < (unsigned)H && (unsigned)gx < (unsigned)W)
        v = cvt(inc[gy * W + gx]);
      tile[ly * 21 + lx] = v;
    }
    __syncthreads();
    float tv[25];
#pragma unroll
    for (int dy = 0; dy < 5; ++dy)
#pragma unroll
      for (int dx = 0; dx < 5; ++dx)
        tv[dy * 5 + dx] = tile[(ty + dy) * 21 + tx + dx];
    const float* wc = wgt + ((size_t)ocb * CIN + c) * 25;
#pragma unroll
    for (int o = 0; o < 8; ++o) {
      const float* wo = wc + (size_t)o * CIN * 25;
#pragma unroll
      for (int t = 0; t < 25; ++t)
        acc[o] = fmaf(tv[t], wo[t], acc[o]);
    }
  }
  int oy = tileY + ty, ox = tileX + tx;
  if (oy < H) {
#pragma unroll
    for (int o = 0; o < 8; ++o)
      stv(&out[((size_t)(b * Cout + ocb + o) * H + oy) * W + ox], acc[o] + bias[ocb + o]);
  }
}

// ------------------------------------------------------- BN batch statistics
// one block per channel; double accumulation from bf16 pre-activations.
__global__ __launch_bounds__(256) void k_bnstats(const bf16* __restrict__ x,
                                                 float* __restrict__ mean,
                                                 float* __restrict__ inv,
                                                 int C, int HW, int B, float eps) {
  __shared__ double s1[256], s2[256];
  int c = blockIdx.x, tid = threadIdx.x;
  double a1 = 0.0, a2 = 0.0;
  for (int b = 0; b < B; ++b) {
    const bf16* p = x + (size_t)(b * C + c) * HW;
    for (int i = tid; i < HW; i += 256) {
      double v = (double)__bfloat162float(p[i]);
      a1 += v;
      a2 += v * v;
    }
  }
  s1[tid] = a1; s2[tid] = a2;
  __syncthreads();
  for (int s = 128; s > 0; s >>= 1) {
    if (tid < s) { s1[tid] += s1[tid + s]; s2[tid] += s2[tid + s]; }
    __syncthreads();
  }
  if (tid == 0) {
    double n = (double)B * (double)HW;
    double m = s1[0] / n;
    double var = s2[0] / n - m * m;
    mean[c] = (float)m;
    inv[c] = rsqrtf((float)var + eps);
  }
}

// ------------------------------------------------------ BN+ReLU in place (bf16)
template <int C, int HW>
__global__ __launch_bounds__(256) void k_bnrelu(bf16* __restrict__ x,
                                                const float* __restrict__ mean,
                                                const float* __restrict__ inv,
                                                const float* __restrict__ g,
                                                const float* __restrict__ be,
                                                int total) {
  int idx = blockIdx.x * 256 + threadIdx.x;
  if (idx >= total) return;
  int c = (idx / HW) % C;
  float v = __bfloat162float(x[idx]);
  v = g[c] * ((v - mean[c]) * inv[c]) + be[c];
  x[idx] = __float2bfloat16(v > 0.f ? v : 0.f);
}

// ------------------------------------------------ BN+ReLU+maxpool2 (NCHW out)
template <int C, int H, int W>
__global__ __launch_bounds__(256) void k_brp(const bf16* __restrict__ x,
                                             bf16* __restrict__ y,
                                             const float* __restrict__ mean,
                                             const float* __restrict__ inv,
                                             const float* __restrict__ g,
                                             const float* __restrict__ be,
                                             int total) {
  constexpr int OW = W / 2, OH = H / 2;
  int idx = blockIdx.x * 256 + threadIdx.x;
  if (idx >= total) return;
  int ox = idx % OW;
  int t = idx / OW;
  int oy = t % OH; t /= OH;
  int c = t % C;
  int b = t / C;
  const bf16* p = x + ((size_t)(b * C + c) * H + oy * 2) * W + ox * 2;
  float m = mean[c], iv = inv[c], gg = g[c], bb = be[c];
  float r = -1e30f;
#pragma unroll
  for (int dy = 0; dy < 2; ++dy)
#pragma unroll
    for (int dx = 0; dx < 2; ++dx) {
      float v = gg * ((__bfloat162float(p[dy * W + dx]) - m) * iv) + bb;
      v = v > 0.f ? v : 0.f;
      r = v > r ? v : r;
    }
  y[idx] = __float2bfloat16(r);
}

// --------------------- stage-3 BN+ReLU+pool, writes transposed fc1 input rows
// x: [64,256,30,16] -> inT[(64 + c*120 + oy*8 + ox)*64 + b]   (bf16)
__global__ __launch_bounds__(256) void k_brp3t(const bf16* __restrict__ x,
                                               bf16* __restrict__ inT,
                                               const float* __restrict__ mean,
                                               const float* __restrict__ inv,
                                               const float* __restrict__ g,
                                               const float* __restrict__ be) {
  constexpr int C = 256, H = 30, W = 16, OH = 15, OW = 8;
  int idx = blockIdx.x * 256 + threadIdx.x;
  if (idx >= 64 * C * OH * OW) return;
  int ox = idx % OW;
  int t = idx / OW;
  int oy = t % OH; t /= OH;
  int c = t % C;
  int b = t / C;
  const bf16* p = x + ((size_t)(b * C + c) * H + oy * 2) * W + ox * 2;
  float m = mean[c], iv = inv[c], gg = g[c], bb = be[c];
  float r = -1e30f;
#pragma unroll
  for (int dy = 0; dy < 2; ++dy)
#pragma unroll
    for (int dx = 0; dx < 2; ++dx) {
      float v = gg * ((__bfloat162float(p[dy * W + dx]) - m) * iv) + bb;
      v = v > 0.f ? v : 0.f;
      r = v > r ? v : r;
    }
  inT[(size_t)(64 + c * 120 + oy * 8 + ox) * 64 + b] = __float2bfloat16(r);
}

// --------------------- fill q rows of fc inputs + zero fc1 accumulator
__global__ __launch_bounds__(256) void k_qinit(const float* __restrict__ q,
                                               bf16* __restrict__ inT,
                                               float* __restrict__ in2T,
                                               float* __restrict__ in3T,
                                               float* __restrict__ z1pre) {
  int idx = blockIdx.x * 256 + threadIdx.x;
  if (idx < 500 * 64) z1pre[idx] = 0.f;
  if (idx >= 4096) return;
  int b = idx >> 6, i = idx & 63;
  float v = q[idx];
  inT[i * 64 + b] = __float2bfloat16(v);
  in2T[i * 64 + b] = v;
  in3T[i * 64 + b] = v;
}

// ----------------------------------------------------------- fc1 (big GEMV)
// inT: [30784][64] bf16; 16 outputs/block, K split 8 ways, atomic combine.
__global__ __launch_bounds__(256) void k_fc1(const bf16* __restrict__ inT,
                                             const float* __restrict__ wgt,
                                             float* __restrict__ z1pre) {
  constexpr int IN = 30784;
  __shared__ float part[4][16][64];
  int ob = blockIdx.x * 16;
  int lane = threadIdx.x & 63, w = threadIdx.x >> 6;
  int i0 = blockIdx.y * 3848 + w * 962;
  int i1 = i0 + 962;
  float acc[16];
#pragma unroll
  for (int k = 0; k < 16; ++k) acc[k] = 0.f;
  for (int i = i0; i < i1; ++i) {
    float v = __bfloat162float(inT[(size_t)i * 64 + lane]);
#pragma unroll
    for (int k = 0; k < 16; ++k) {
      int o = ob + k; o = o < 500 ? o : 499;
      acc[k] = fmaf(v, wgt[(size_t)o * IN + i], acc[k]);
    }
  }
#pragma unroll
  for (int k = 0; k < 16; ++k) part[w][k][lane] = acc[k];
  __syncthreads();
  int k4 = threadIdx.x >> 6;
  for (int kk = k4; kk < 16; kk += 4) {
    int o = ob + kk;
    if (o < 500) {
      float s = part[0][kk][lane] + part[1][kk][lane] + part[2][kk][lane] + part[3][kk][lane];
      atomicAdd(&z1pre[o * 64 + lane], s);
    }
  }
}

// -------------------------------------------- fc1 epilogue: bias+relu -> in2T
__global__ __launch_bounds__(256) void k_fc1ep(const float* __restrict__ z1pre,
                                               const float* __restrict__ bias,
                                               float* __restrict__ in2T) {
  int idx = blockIdx.x * 256 + threadIdx.x;
  if (idx >= 500 * 64) return;
  int o = idx >> 6;
  float v = z1pre[idx] + bias[o];
  in2T[idx + 64 * 64] = v > 0.f ? v : 0.f;
}

// ------------------------------------------------- small fc (fc2 / fc3)
// mode 0: relu, write outT[(64+o)*64+lane]; mode 1: plain, write out[lane*2+o]
__global__ __launch_bounds__(256) void k_fc_small(const float* __restrict__ inT,
                                                  const float* __restrict__ wgt,
                                                  const float* __restrict__ bias,
                                                  float* __restrict__ out,
                                                  int IN, int mode) {
  __shared__ float part[4][64];
  int o = blockIdx.x;
  int lane = threadIdx.x & 63, w = threadIdx.x >> 6;
  float acc = 0.f;
  for (int i = w; i < IN; i += 4)
    acc = fmaf(inT[(size_t)i * 64 + lane], wgt[(size_t)o * IN + i], acc);
  part[w][lane] = acc;
  __syncthreads();
  if (threadIdx.x < 64) {
    float s = part[0][lane] + part[1][lane] + part[2][lane] + part[3][lane] + bias[o];
    if (mode == 0) {
      s = s > 0.f ? s : 0.f;
      out[(64 + o) * 64 + lane] = s;
    } else {
      out[lane * 2 + o] = s;
    }
  }
}

// ============================================================================
extern "C" void kernel_launch(void* const* d_in, const int* in_sizes, int n_in,
                              void* d_out, int out_size, void* d_ws, size_t ws_size,
                              hipStream_t stream) {
  const float* x      = (const float*)d_in[0];
  const float* qvec   = (const float*)d_in[1];
  const float* basis  = (const float*)d_in[2];
  const float* w1a    = (const float*)d_in[3];
  const float* b1a    = (const float*)d_in[4];
  const float* g1a    = (const float*)d_in[5];
  const float* be1a   = (const float*)d_in[6];
  const float* w1b    = (const float*)d_in[7];
  const float* b1b    = (const float*)d_in[8];
  const float* g1b    = (const float*)d_in[9];
  const float* be1b   = (const float*)d_in[10];
  const float* w2a    = (const float*)d_in[11];
  const float* b2a    = (const float*)d_in[12];
  const float* g2a    = (const float*)d_in[13];
  const float* be2a   = (const float*)d_in[14];
  const float* w3a    = (const float*)d_in[15];
  const float* b3a    = (const float*)d_in[16];
  const float* g3a    = (const float*)d_in[17];
  const float* be3a   = (const float*)d_in[18];
  const float* fc1w   = (const float*)d_in[19];
  const float* fc1b   = (const float*)d_in[20];
  const float* fc2w   = (const float*)d_in[21];
  const float* fc2b   = (const float*)d_in[22];
  const float* fc3w   = (const float*)d_in[23];
  const float* fc3b   = (const float*)d_in[24];
  float* out = (float*)d_out;

  char* base = (char*)d_ws;
  // Arena A: 62,914,560 bytes; Arena B: 62,914,560 bytes; then small region.
  constexpr size_t ARENA = 62914560;         // 64*64*120*64 * 2B
  char* arenaA = base;
  char* arenaB = base + ARENA;
  char* smallr = base + 2 * ARENA;

  float* xd   = (float*)arenaA;              // 16,777,216 B
  bf16*  A    = (bf16*)arenaA;               // pre1a, 62,914,560 B
  bf16*  P1   = (bf16*)arenaA;               // [64,64,60,32]  15,728,640 B
  bf16*  P2   = (bf16*)arenaA;               // [64,128,30,16]  7,864,320 B
  bf16*  inT  = (bf16*)arenaA;               // [30784][64]     3,940,352 B

  float* feat = (float*)arenaB;              // 1,966,080 B
  bf16*  Bb   = (bf16*)arenaB;               // pre1b, 62,914,560 B
  bf16*  C2   = (bf16*)arenaB;               // [64,128,60,32] 31,457,280 B
  bf16*  D3   = (bf16*)arenaB;               // [64,256,30,16] 15,728,640 B

  float* in2T = (float*)smallr;              // 564*64*4 = 144,384 B
  float* in3T = (float*)(smallr + 144384);   // 144,384 B
  float* z1p  = (float*)(smallr + 288768);   // 128,000 B
  float* S1A  = (float*)(smallr + 416768);   // 128 floats (mean64+inv64)
  float* S1B  = S1A + 128;
  float* S2A  = S1B + 128;                   // 256 floats
  float* S3A  = S2A + 256;                   // 512 floats

  k_qinit<<<125, 256, 0, stream>>>(qvec, inT, in2T, in3T, z1p);
  // NOTE: inT q-rows written again implicitly ok — but inT aliases arena A
  // which is clobbered by xd/A/P1/P2 first. Re-run q-init for inT later.

  k_dct<<<64 * 8, 256, 0, stream>>>(x, basis, xd);
  k_hist<<<4096, 256, 0, stream>>>(xd, feat);

  // conv1a: [64,1,120,64] -> pre1a bf16
  k_conv5<1, 120, 64, float, bf16><<<dim3(32, 64, 8), 256, 0, stream>>>(feat, w1a, b1a, A, 64);
  k_bnstats<<<64, 256, 0, stream>>>(A, S1A, S1A + 64, 64, 7680, 64, 1e-5f);
  k_bnrelu<64, 7680><<<122880, 256, 0, stream>>>(A, S1A, S1A + 64, g1a, be1a, 31457280);

  // conv1b: -> pre1b, BN, relu+pool -> P1 [64,64,60,32]
  k_conv5<64, 120, 64, bf16, bf16><<<dim3(32, 64, 8), 256, 0, stream>>>(A, w1b, b1b, Bb, 64);
  k_bnstats<<<64, 256, 0, stream>>>(Bb, S1B, S1B + 64, 64, 7680, 64, 1e-5f);
  k_brp<64, 120, 64><<<30720, 256, 0, stream>>>(Bb, P1, S1B, S1B + 64, g1b, be1b, 7864320);

  // conv2a: -> pre2a [64,128,60,32], BN, relu+pool -> P2 [64,128,30,16]
  k_conv5<64, 60, 32, bf16, bf16><<<dim3(8, 64, 16), 256, 0, stream>>>(P1, w2a, b2a, C2, 128);
  k_bnstats<<<128, 256, 0, stream>>>(C2, S2A, S2A + 128, 128, 1920, 64, 1e-5f);
  k_brp<128, 60, 32><<<15360, 256, 0, stream>>>(C2, P2, S2A, S2A + 128, g2a, be2a, 3932160);

  // conv3a: -> pre3a [64,256,30,16], BN, relu+pool -> inT rows (transposed)
  k_conv5<128, 30, 16, bf16, bf16><<<dim3(2, 64, 32), 256, 0, stream>>>(P2, w3a, b3a, D3, 256);
  k_bnstats<<<256, 256, 0, stream>>>(D3, S3A, S3A + 256, 256, 480, 64, 1e-5f);
  // inT aliases arena A (P2 dead after conv3a). Re-write q rows, then conv rows.
  k_qinit<<<125, 256, 0, stream>>>(qvec, inT, in2T, in3T, z1p);
  k_brp3t<<<7680, 256, 0, stream>>>(D3, inT, S3A, S3A + 256, g3a, be3a);

  // FC head
  k_fc1<<<dim3(32, 8), 256, 0, stream>>>(inT, fc1w, z1p);
  k_fc1ep<<<125, 256, 0, stream>>>(z1p, fc1b, in2T);
  k_fc_small<<<500, 256, 0, stream>>>(in2T, fc2w, fc2b, in3T, 564, 0);
  k_fc_small<<<2, 256, 0, stream>>>(in3T, fc3w, fc3b, out, 564, 1);
}

// Round 3
// 2161.417 us; speedup vs baseline: 2.5977x; 2.5977x over previous
//
#include <hip/hip_runtime.h>
#include <hip/hip_bf16.h>
#include <math.h>

// ============================================================================
// DoubleJpeg round 2: MFMA implicit-GEMM convs, NHWC bf16 activations.
//   conv bias dropped (cancels exactly in training-mode BN).
//   conv weights: hi+lo bf16 split -> effective fp32 weight precision.
// Arena A (62.91 MB): xd(fp32) -> pre1a A -> P1 -> P2 -> inT(fp32)
// Arena B (62.91 MB): feat(fp32) -> pre1b Bb -> C2 -> D3
// Small: in2T/in3T/z1p/ACC/stats + split conv weights (4.5 MB).
// Total ws ~130.8 MB.
// ============================================================================

typedef __attribute__((ext_vector_type(8))) short bf16x8;
typedef __attribute__((ext_vector_type(4))) float f32x4;
typedef __hip_bfloat16 hbf;

#define GAMMA_F 1.0e6f

__device__ __forceinline__ unsigned short f2b(float f) {
  hbf h = __float2bfloat16(f);
  return *(unsigned short*)&h;
}
__device__ __forceinline__ float b2f(unsigned short u) {
  union { unsigned int i; float f; } x;
  x.i = ((unsigned int)u) << 16;
  return x.f;
}

// ---------------------------------------------------------------- DCT kernel
__global__ __launch_bounds__(256) void k_dct(const float* __restrict__ x,
                                             const float* __restrict__ basis,
                                             float* __restrict__ xd) {
  __shared__ float bT[4096];     // bT[p*64+k] = basis[k*64+p]
  __shared__ float pix[4][64];
  int tid = threadIdx.x;
  for (int e = tid; e < 4096; e += 256)
    bT[e] = basis[(e & 63) * 64 + (e >> 6)];
  __syncthreads();
  int w = tid >> 6, lane = tid & 63;
  int b = blockIdx.x >> 3;
  int br = ((blockIdx.x & 7) << 2) + w;
  const float* xb = x + (size_t)b * 65536;
  float* xdb = xd + (size_t)b * 65536;
  for (int bc = 0; bc < 32; ++bc) {
    __syncthreads();
    pix[w][lane] = xb[(br * 8 + (lane >> 3)) * 256 + bc * 8 + (lane & 7)];
    __syncthreads();
    float acc = 0.f;
#pragma unroll
    for (int p = 0; p < 64; ++p)
      acc = fmaf(bT[p * 64 + lane], pix[w][p], acc);
    xdb[lane * 1024 + br * 32 + bc] = acc;
  }
}

// ---------------------------------------------------- soft histogram -> feat
__global__ __launch_bounds__(256) void k_hist(const float* __restrict__ xd,
                                              float* __restrict__ feat) {
  __shared__ float bins[120];
  int tid = threadIdx.x;
  int bc = blockIdx.x;
  int b = bc >> 6, c = bc & 63;
  if (tid < 120) bins[tid] = 0.f;
  __syncthreads();
  const float* p = xd + (size_t)bc * 1024;
#pragma unroll
  for (int k = 0; k < 4; ++k) {
    float v = p[tid + k * 256];
    float fl = floorf(v);
    float u = v - fl;
    float sa = 1.f / (1.f + expf(-GAMMA_F * u));
    float sb = 1.f / (1.f + expf(-GAMMA_F * (u - 1.f)));
    int j = (int)fl + 60;
    if ((unsigned)j < 120u) atomicAdd(&bins[j], sa - sb);
    if (sa < 1.f && (unsigned)(j - 1) < 120u) atomicAdd(&bins[j - 1], 1.f - sa);
    if (sb > 0.f && (unsigned)(j + 1) < 120u) atomicAdd(&bins[j + 1], sb);
  }
  __syncthreads();
  if (tid < 120) feat[((size_t)b * 120 + tid) * 64 + c] = bins[tid] * (1.f / 1024.f);
}

// ------------------------------------------- weight prep: fp32 -> bf16 hi+lo
// in: w[oc][ic][5][5] fp32 ; out: wt[t][oc][ic] (hi), wt+n (lo)
__global__ __launch_bounds__(256) void k_prepw(const float* __restrict__ w,
                                               unsigned short* __restrict__ wt,
                                               int OC, int IC) {
  int n = OC * IC * 25;
  int idx = blockIdx.x * 256 + threadIdx.x;
  if (idx >= n) return;
  int t = idx / (OC * IC);
  int r = idx % (OC * IC);
  int o = r / IC, i = r % IC;
  float f = w[(o * IC + i) * 25 + t];
  unsigned short hi = f2b(f);
  float lo = f - b2f(hi);
  wt[idx] = hi;
  wt[n + idx] = f2b(lo);
}

// ----------------------------------------------- conv1a (CIN=1), direct fp32
// feat [64][120][64] fp32 -> A [64][120][64][64oc] bf16. grid (32, 64, 8).
__global__ __launch_bounds__(256) void k_conv1a(const float* __restrict__ in,
                                                const float* __restrict__ wgt,
                                                unsigned short* __restrict__ out) {
  __shared__ float tile[20 * 21];
  int tx = threadIdx.x & 15, ty = threadIdx.x >> 4;
  int tileX = (blockIdx.x & 3) * 16, tileY = (blockIdx.x >> 2) * 16;
  int b = blockIdx.y, ocb = blockIdx.z * 8;
  const float* inc = in + (size_t)b * 7680;
  for (int e = threadIdx.x; e < 400; e += 256) {
    int ly = e / 20, lx = e % 20;
    int gy = tileY - 2 + ly, gx = tileX - 2 + lx;
    float v = 0.f;
    if ((unsigned)gy < 120u && (unsigned)gx < 64u) v = inc[gy * 64 + gx];
    tile[ly * 21 + lx] = v;
  }
  __syncthreads();
  float tv[25];
#pragma unroll
  for (int dy = 0; dy < 5; ++dy)
#pragma unroll
    for (int dx = 0; dx < 5; ++dx)
      tv[dy * 5 + dx] = tile[(ty + dy) * 21 + tx + dx];
  float acc[8];
#pragma unroll
  for (int o = 0; o < 8; ++o) {
    const float* wo = wgt + (size_t)(ocb + o) * 25;
    float a = 0.f;
#pragma unroll
    for (int t = 0; t < 25; ++t) a = fmaf(tv[t], wo[t], a);
    acc[o] = a;
  }
  int oy = tileY + ty, ox = tileX + tx;
  if (oy < 120) {
    size_t base = (((size_t)b * 120 + oy) * 64 + ox) * 64 + ocb;
    ushort4 p0, p1;
    p0.x = f2b(acc[0]); p0.y = f2b(acc[1]); p0.z = f2b(acc[2]); p0.w = f2b(acc[3]);
    p1.x = f2b(acc[4]); p1.y = f2b(acc[5]); p1.z = f2b(acc[6]); p1.w = f2b(acc[7]);
    *(ushort4*)(out + base) = p0;
    *(ushort4*)(out + base + 4) = p1;
  }
}

// ---------------------------------------------- MFMA implicit-GEMM 5x5 conv
// NHWC bf16 in/out. Wave: 4 M-tiles (64 oc) x 4 N-tiles (64 px).
// grid (ceil(H/WGR), B=64, OC/64).  Weights: wt[t][oc][CIN] hi, +NW lo.
template <int CIN, int H, int W, int RPW, int OC>
__global__ __launch_bounds__(256) void k_convM(const unsigned short* __restrict__ in,
                                               const unsigned short* __restrict__ wt,
                                               unsigned short* __restrict__ out) {
  constexpr int WGR = 4 * RPW, XC = W / 16, LW = W + 4, LR = WGR + 4;
  constexpr int NW = OC * CIN * 25;
  __shared__ short lds[LR * LW * 32];
  int tid = threadIdx.x;
  int w = tid >> 6, lane = tid & 63, l15 = lane & 15, q = lane >> 4;
  int y0 = blockIdx.x * WGR, b = blockIdx.y, oc0 = blockIdx.z * 64;
  f32x4 acc[4][4];
#pragma unroll
  for (int mt = 0; mt < 4; ++mt)
#pragma unroll
    for (int nt = 0; nt < 4; ++nt) acc[mt][nt] = 0.f;

  for (int icb = 0; icb < CIN / 32; ++icb) {
    __syncthreads();
    for (int e = tid; e < LR * LW * 4; e += 256) {
      int q4 = e & 3, c = (e >> 2) % LW, lr = (e >> 2) / LW;
      int y = y0 - 2 + lr, x = c - 2;
      bf16x8 v = 0;
      if ((unsigned)y < (unsigned)H && (unsigned)x < (unsigned)W)
        v = *(const bf16x8*)(in + (((size_t)b * H + y) * W + x) * CIN + icb * 32 + q4 * 8);
      *(bf16x8*)&lds[(lr * LW + c) * 32 + q4 * 8] = v;
    }
    __syncthreads();
#pragma unroll
    for (int dy = 0; dy < 5; ++dy)
#pragma unroll
      for (int dx = 0; dx < 5; ++dx) {
        int t = dy * 5 + dx;
        bf16x8 ah[4], al[4];
#pragma unroll
        for (int mt = 0; mt < 4; ++mt) {
          const unsigned short* wp =
              wt + ((size_t)(t * OC + oc0 + mt * 16 + l15) * CIN + icb * 32 + q * 8);
          ah[mt] = *(const bf16x8*)wp;
          al[mt] = *(const bf16x8*)(wp + NW);
        }
#pragma unroll
        for (int nt = 0; nt < 4; ++nt) {
          int lr = w * RPW + nt / XC + dy;
          int c = (nt % XC) * 16 + l15 + dx;
          bf16x8 bv = *(const bf16x8*)&lds[(lr * LW + c) * 32 + q * 8];
#pragma unroll
          for (int mt = 0; mt < 4; ++mt) {
            acc[mt][nt] = __builtin_amdgcn_mfma_f32_16x16x32_bf16(al[mt], bv, acc[mt][nt], 0, 0, 0);
            acc[mt][nt] = __builtin_amdgcn_mfma_f32_16x16x32_bf16(ah[mt], bv, acc[mt][nt], 0, 0, 0);
          }
        }
      }
  }
#pragma unroll
  for (int nt = 0; nt < 4; ++nt) {
    int y = y0 + w * RPW + nt / XC;
    if (y >= H) continue;
    int x = (nt % XC) * 16 + l15;
    size_t pbase = (((size_t)b * H + y) * W + x) * OC + oc0 + q * 4;
#pragma unroll
    for (int mt = 0; mt < 4; ++mt) {
      ushort4 pk;
      pk.x = f2b(acc[mt][nt][0]);
      pk.y = f2b(acc[mt][nt][1]);
      pk.z = f2b(acc[mt][nt][2]);
      pk.w = f2b(acc[mt][nt][3]);
      *(ushort4*)(out + pbase + mt * 16) = pk;
    }
  }
}

// --------------------------------------- BN stats stage 1: partial sums (f32)
// grid (chunks, C/64), block 256 = 64c x 4p. acc[c]=sum, acc[C+c]=sumsq.
__global__ __launch_bounds__(256) void k_bnstats2(const unsigned short* __restrict__ x,
                                                  float* __restrict__ acc,
                                                  int C, int P) {
  __shared__ float r1[256], r2[256];
  int ci = threadIdx.x & 63, pq = threadIdx.x >> 6;
  int c = blockIdx.y * 64 + ci;
  float s1 = 0.f, s2 = 0.f;
  size_t base = (size_t)blockIdx.x * P;
  for (int k = pq; k < P; k += 4) {
    float v = b2f(x[(base + k) * C + c]);
    s1 += v;
    s2 += v * v;
  }
  r1[pq * 64 + ci] = s1;
  r2[pq * 64 + ci] = s2;
  __syncthreads();
  if (pq == 0) {
    float t1 = r1[ci] + r1[64 + ci] + r1[128 + ci] + r1[192 + ci];
    float t2 = r2[ci] + r2[64 + ci] + r2[128 + ci] + r2[192 + ci];
    atomicAdd(&acc[c], t1);
    atomicAdd(&acc[C + c], t2);
  }
}

// --------------------------------------- BN stats stage 2: finalize mean/inv
__global__ __launch_bounds__(256) void k_bnfin(const float* __restrict__ acc,
                                               float* __restrict__ stats,
                                               int C, float invN) {
  int c = threadIdx.x + blockIdx.x * 256;
  if (c >= C) return;
  float m = acc[c] * invN;
  float v = acc[C + c] * invN - m * m;
  stats[c] = m;
  stats[C + c] = rsqrtf(v + 1e-5f);
}

// ------------------------------------------------- BN+ReLU in place (NHWC)
__global__ __launch_bounds__(256) void k_bnrelu1a(unsigned short* __restrict__ x,
                                                  const float* __restrict__ stats,
                                                  const float* __restrict__ g,
                                                  const float* __restrict__ be) {
  int idx = blockIdx.x * 256 + threadIdx.x;
  int c = idx & 63;
  float v = b2f(x[idx]);
  v = g[c] * ((v - stats[c]) * stats[64 + c]) + be[c];
  x[idx] = f2b(v > 0.f ? v : 0.f);
}

// --------------------------------------- BN+ReLU+maxpool2 NHWC -> NHWC
template <int C, int H, int W>
__global__ __launch_bounds__(256) void k_brp(const unsigned short* __restrict__ x,
                                             unsigned short* __restrict__ y,
                                             const float* __restrict__ stats,
                                             const float* __restrict__ g,
                                             const float* __restrict__ be) {
  constexpr int OH = H / 2, OW = W / 2;
  int idx = blockIdx.x * 256 + threadIdx.x;
  int c = idx % C;
  int t = idx / C;
  int ox = t % OW; t /= OW;
  int oy = t % OH;
  int b = t / OH;
  float m = stats[c], iv = stats[C + c], gg = g[c], bb = be[c];
  const unsigned short* p = x + ((size_t)(b * H + oy * 2) * W + ox * 2) * C + c;
  float r = 0.f;
#pragma unroll
  for (int dy = 0; dy < 2; ++dy)
#pragma unroll
    for (int dx = 0; dx < 2; ++dx) {
      float v = gg * ((b2f(p[((size_t)dy * W + dx) * C]) - m) * iv) + bb;
      v = v > 0.f ? v : 0.f;
      r = v > r ? v : r;
    }
  y[idx] = f2b(r);
}

// ---- stage-3 BN+ReLU+pool + transpose into fc1 rows: inT[(64+c*120+s)*64+b]
// in D3 [64][30][16][256] bf16 ; grid 120 (s = oy*8+ox), block 256.
__global__ __launch_bounds__(256) void k_brp3t(const unsigned short* __restrict__ x,
                                               float* __restrict__ inT,
                                               const float* __restrict__ stats,
                                               const float* __restrict__ g,
                                               const float* __restrict__ be) {
  __shared__ float tile[64 * 65];
  int s = blockIdx.x;
  int oy = s >> 3, ox = s & 7;
  int ci = threadIdx.x & 63, bq = threadIdx.x >> 6;
  for (int cs = 0; cs < 4; ++cs) {
    int c = cs * 64 + ci;
    float m = stats[c], iv = stats[256 + c], gg = g[c], bb = be[c];
    __syncthreads();
    for (int b = bq; b < 64; b += 4) {
      float mx = 0.f;
#pragma unroll
      for (int qq = 0; qq < 4; ++qq) {
        int yy = oy * 2 + (qq >> 1), xx = ox * 2 + (qq & 1);
        float v = b2f(x[((size_t)(b * 30 + yy) * 16 + xx) * 256 + c]);
        v = gg * ((v - m) * iv) + bb;
        v = v > 0.f ? v : 0.f;
        mx = v > mx ? v : mx;
      }
      tile[ci * 65 + b] = mx;
    }
    __syncthreads();
    for (int e = threadIdx.x; e < 4096; e += 256) {
      int cc = e >> 6, bb2 = e & 63;
      inT[(size_t)(64 + (cs * 64 + cc) * 120 + s) * 64 + bb2] = tile[cc * 65 + bb2];
    }
  }
}

// -------------------- q rows of fc inputs + zero fc1 accumulator + BN accums
__global__ __launch_bounds__(256) void k_qinit(const float* __restrict__ q,
                                               float* __restrict__ inT,
                                               float* __restrict__ in2T,
                                               float* __restrict__ in3T,
                                               float* __restrict__ z1pre,
                                               float* __restrict__ bnacc) {
  int idx = blockIdx.x * 256 + threadIdx.x;
  if (idx < 32000) z1pre[idx] = 0.f;
  else if (idx < 33024) bnacc[idx - 32000] = 0.f;
  if (idx >= 4096) return;
  int b = idx >> 6, i = idx & 63;
  float v = q[idx];
  inT[i * 64 + b] = v;
  in2T[i * 64 + b] = v;
  in3T[i * 64 + b] = v;
}

// ----------------------------------------------------------- fc1 (big GEMV)
__global__ __launch_bounds__(256) void k_fc1(const float* __restrict__ inT,
                                             const float* __restrict__ wgt,
                                             float* __restrict__ z1pre) {
  constexpr int IN = 30784;
  __shared__ float part[4][16][64];
  int ob = blockIdx.x * 16;
  int lane = threadIdx.x & 63, w = threadIdx.x >> 6;
  int i0 = blockIdx.y * 3848 + w * 962;
  int i1 = i0 + 962;
  float acc[16];
#pragma unroll
  for (int k = 0; k < 16; ++k) acc[k] = 0.f;
  for (int i = i0; i < i1; ++i) {
    float v = inT[(size_t)i * 64 + lane];
#pragma unroll
    for (int k = 0; k < 16; ++k) {
      int o = ob + k; o = o < 500 ? o : 499;
      acc[k] = fmaf(v, wgt[(size_t)o * IN + i], acc[k]);
    }
  }
#pragma unroll
  for (int k = 0; k < 16; ++k) part[w][k][lane] = acc[k];
  __syncthreads();
  int k4 = threadIdx.x >> 6;
  for (int kk = k4; kk < 16; kk += 4) {
    int o = ob + kk;
    if (o < 500) {
      float s = part[0][kk][lane] + part[1][kk][lane] + part[2][kk][lane] + part[3][kk][lane];
      atomicAdd(&z1pre[o * 64 + lane], s);
    }
  }
}

__global__ __launch_bounds__(256) void k_fc1ep(const float* __restrict__ z1pre,
                                               const float* __restrict__ bias,
                                               float* __restrict__ in2T) {
  int idx = blockIdx.x * 256 + threadIdx.x;
  if (idx >= 500 * 64) return;
  int o = idx >> 6;
  float v = z1pre[idx] + bias[o];
  in2T[idx + 64 * 64] = v > 0.f ? v : 0.f;
}

__global__ __launch_bounds__(256) void k_fc_small(const float* __restrict__ inT,
                                                  const float* __restrict__ wgt,
                                                  const float* __restrict__ bias,
                                                  float* __restrict__ out,
                                                  int IN, int mode) {
  __shared__ float part[4][64];
  int o = blockIdx.x;
  int lane = threadIdx.x & 63, w = threadIdx.x >> 6;
  float acc = 0.f;
  for (int i = w; i < IN; i += 4)
    acc = fmaf(inT[(size_t)i * 64 + lane], wgt[(size_t)o * IN + i], acc);
  part[w][lane] = acc;
  __syncthreads();
  if (threadIdx.x < 64) {
    float s = part[0][lane] + part[1][lane] + part[2][lane] + part[3][lane] + bias[o];
    if (mode == 0) {
      s = s > 0.f ? s : 0.f;
      out[(64 + o) * 64 + lane] = s;
    } else {
      out[lane * 2 + o] = s;
    }
  }
}

// ============================================================================
extern "C" void kernel_launch(void* const* d_in, const int* in_sizes, int n_in,
                              void* d_out, int out_size, void* d_ws, size_t ws_size,
                              hipStream_t stream) {
  const float* x      = (const float*)d_in[0];
  const float* qvec   = (const float*)d_in[1];
  const float* basis  = (const float*)d_in[2];
  const float* w1a    = (const float*)d_in[3];
  const float* g1a    = (const float*)d_in[5];
  const float* be1a   = (const float*)d_in[6];
  const float* w1b    = (const float*)d_in[7];
  const float* g1b    = (const float*)d_in[9];
  const float* be1b   = (const float*)d_in[10];
  const float* w2a    = (const float*)d_in[11];
  const float* g2a    = (const float*)d_in[13];
  const float* be2a   = (const float*)d_in[14];
  const float* w3a    = (const float*)d_in[15];
  const float* g3a    = (const float*)d_in[17];
  const float* be3a   = (const float*)d_in[18];
  const float* fc1w   = (const float*)d_in[19];
  const float* fc1b   = (const float*)d_in[20];
  const float* fc2w   = (const float*)d_in[21];
  const float* fc2b   = (const float*)d_in[22];
  const float* fc3w   = (const float*)d_in[23];
  const float* fc3b   = (const float*)d_in[24];
  float* out = (float*)d_out;

  char* base = (char*)d_ws;
  constexpr size_t ARENA = 62914560;
  char* arenaA = base;
  char* arenaB = base + ARENA;
  char* sm     = base + 2 * ARENA;

  float*          xd   = (float*)arenaA;
  unsigned short* A    = (unsigned short*)arenaA;  // pre1a NHWC [64][120][64][64]
  unsigned short* P1   = (unsigned short*)arenaA;  // [64][60][32][64]
  unsigned short* P2   = (unsigned short*)arenaA;  // [64][30][16][128]
  float*          inT  = (float*)arenaA;           // [30784][64] fp32

  float*          feat = (float*)arenaB;           // [64][120][64] fp32
  unsigned short* Bb   = (unsigned short*)arenaB;  // pre1b [64][120][64][64]
  unsigned short* C2   = (unsigned short*)arenaB;  // [64][60][32][128]
  unsigned short* D3   = (unsigned short*)arenaB;  // [64][30][16][256]

  float* in2T = (float*)sm;                    // 144,384 B
  float* in3T = (float*)(sm + 144384);         // 144,384 B
  float* z1p  = (float*)(sm + 288768);         // 128,000 B
  float* ACC  = (float*)(sm + 416768);         // 4,096 B (1a:0,1b:128,2a:256,3a:512)
  float* S1A  = (float*)(sm + 420864);         // 128 f
  float* S1B  = (float*)(sm + 421376);         // 128 f
  float* S2A  = (float*)(sm + 421888);         // 256 f
  float* S3A  = (float*)(sm + 422912);         // 512 f
  unsigned short* WT1 = (unsigned short*)(sm + 424960);   // 409,600 B
  unsigned short* WT2 = (unsigned short*)(sm + 834560);   // 819,200 B
  unsigned short* WT3 = (unsigned short*)(sm + 1653760);  // 3,276,800 B

  k_qinit<<<130, 256, 0, stream>>>(qvec, inT, in2T, in3T, z1p, ACC);
  k_prepw<<<400, 256, 0, stream>>>(w1b, WT1, 64, 64);
  k_prepw<<<800, 256, 0, stream>>>(w2a, WT2, 128, 64);
  k_prepw<<<3200, 256, 0, stream>>>(w3a, WT3, 256, 128);

  k_dct<<<64 * 8, 256, 0, stream>>>(x, basis, xd);
  k_hist<<<4096, 256, 0, stream>>>(xd, feat);

  // conv1a (direct) -> A, BN(stats+relu in place)
  k_conv1a<<<dim3(32, 64, 8), 256, 0, stream>>>(feat, w1a, A);
  k_bnstats2<<<dim3(256, 1), 256, 0, stream>>>(A, ACC, 64, 1920);
  k_bnfin<<<1, 64, 0, stream>>>(ACC, S1A, 64, 1.f / 491520.f);
  k_bnrelu1a<<<122880, 256, 0, stream>>>(A, S1A, g1a, be1a);

  // conv1b (MFMA) -> Bb, BN stats, BN+relu+pool -> P1
  k_convM<64, 120, 64, 1, 64><<<dim3(30, 64, 1), 256, 0, stream>>>(A, WT1, Bb);
  k_bnstats2<<<dim3(256, 1), 256, 0, stream>>>(Bb, ACC + 128, 64, 1920);
  k_bnfin<<<1, 64, 0, stream>>>(ACC + 128, S1B, 64, 1.f / 491520.f);
  k_brp<64, 120, 64><<<30720, 256, 0, stream>>>(Bb, P1, S1B, g1b, be1b);

  // conv2a (MFMA) -> C2, stats, pool -> P2
  k_convM<64, 60, 32, 2, 128><<<dim3(8, 64, 2), 256, 0, stream>>>(P1, WT2, C2);
  k_bnstats2<<<dim3(64, 2), 256, 0, stream>>>(C2, ACC + 256, 128, 1920);
  k_bnfin<<<1, 128, 0, stream>>>(ACC + 256, S2A, 128, 1.f / 122880.f);
  k_brp<128, 60, 32><<<15360, 256, 0, stream>>>(C2, P2, S2A, g2a, be2a);

  // conv3a (MFMA) -> D3, stats, pool+transpose -> inT
  k_convM<128, 30, 16, 4, 256><<<dim3(2, 64, 4), 256, 0, stream>>>(P2, WT3, D3);
  k_bnstats2<<<dim3(16, 4), 256, 0, stream>>>(D3, ACC + 512, 256, 1920);
  k_bnfin<<<1, 256, 0, stream>>>(ACC + 512, S3A, 256, 1.f / 30720.f);
  k_qinit<<<130, 256, 0, stream>>>(qvec, inT, in2T, in3T, z1p, ACC);  // re-init q rows of inT + z1p
  k_brp3t<<<120, 256, 0, stream>>>(D3, inT, S3A, g3a, be3a);

  // FC head
  k_fc1<<<dim3(32, 8), 256, 0, stream>>>(inT, fc1w, z1p);
  k_fc1ep<<<125, 256, 0, stream>>>(z1p, fc1b, in2T);
  k_fc_small<<<500, 256, 0, stream>>>(in2T, fc2w, fc2b, in3T, 564, 0);
  k_fc_small<<<2, 256, 0, stream>>>(in3T, fc3w, fc3b, out, 564, 1);
}

// Round 4
// 1807.224 us; speedup vs baseline: 3.1068x; 1.1960x over previous
//
#include <hip/hip_runtime.h>
#include <math.h>

// ============================================================================
// DoubleJpeg round 3: fp16 single-MFMA convs (was bf16 hi+lo = 2x MFMA),
// bank-conflict-free ic-chunk-major LDS, wider N-tiles per wave.
// Arena A (62.91 MB): xd(fp32) -> pre1a A -> P1 -> P2 -> inT(fp32)
// Arena B (62.91 MB): feat(fp32) -> pre1b Bb -> C2 -> D3
// ============================================================================

typedef __attribute__((ext_vector_type(8))) _Float16 f16x8;
typedef __attribute__((ext_vector_type(4))) float f32x4;

#define GAMMA_F 1.0e6f

__device__ __forceinline__ unsigned short f2h(float f) {
  _Float16 h = (_Float16)f;
  union { _Float16 h; unsigned short u; } x; x.h = h; return x.u;
}
__device__ __forceinline__ float h2f(unsigned short u) {
  union { unsigned short u; _Float16 h; } x; x.u = u; return (float)x.h;
}

// ---------------------------------------------------------------- DCT kernel
__global__ __launch_bounds__(256) void k_dct(const float* __restrict__ x,
                                             const float* __restrict__ basis,
                                             float* __restrict__ xd) {
  __shared__ float bT[4096];
  __shared__ float pix[4][64];
  int tid = threadIdx.x;
  for (int e = tid; e < 4096; e += 256)
    bT[e] = basis[(e & 63) * 64 + (e >> 6)];
  __syncthreads();
  int w = tid >> 6, lane = tid & 63;
  int b = blockIdx.x >> 3;
  int br = ((blockIdx.x & 7) << 2) + w;
  const float* xb = x + (size_t)b * 65536;
  float* xdb = xd + (size_t)b * 65536;
  for (int bc = 0; bc < 32; ++bc) {
    __syncthreads();
    pix[w][lane] = xb[(br * 8 + (lane >> 3)) * 256 + bc * 8 + (lane & 7)];
    __syncthreads();
    float acc = 0.f;
#pragma unroll
    for (int p = 0; p < 64; ++p)
      acc = fmaf(bT[p * 64 + lane], pix[w][p], acc);
    xdb[lane * 1024 + br * 32 + bc] = acc;
  }
}

// ---------------------------------------------------- soft histogram -> feat
__global__ __launch_bounds__(256) void k_hist(const float* __restrict__ xd,
                                              float* __restrict__ feat) {
  __shared__ float bins[120];
  int tid = threadIdx.x;
  int bc = blockIdx.x;
  int b = bc >> 6, c = bc & 63;
  if (tid < 120) bins[tid] = 0.f;
  __syncthreads();
  const float* p = xd + (size_t)bc * 1024;
#pragma unroll
  for (int k = 0; k < 4; ++k) {
    float v = p[tid + k * 256];
    float fl = floorf(v);
    float u = v - fl;
    float sa = 1.f / (1.f + expf(-GAMMA_F * u));
    float sb = 1.f / (1.f + expf(-GAMMA_F * (u - 1.f)));
    int j = (int)fl + 60;
    if ((unsigned)j < 120u) atomicAdd(&bins[j], sa - sb);
    if (sa < 1.f && (unsigned)(j - 1) < 120u) atomicAdd(&bins[j - 1], 1.f - sa);
    if (sb > 0.f && (unsigned)(j + 1) < 120u) atomicAdd(&bins[j + 1], sb);
  }
  __syncthreads();
  if (tid < 120) feat[((size_t)b * 120 + tid) * 64 + c] = bins[tid] * (1.f / 1024.f);
}

// ------------------------------------------- weight prep: fp32 -> fp16
// in: w[oc][ic][5][5] fp32 ; out: wt[t][oc][ic]
__global__ __launch_bounds__(256) void k_prepw(const float* __restrict__ w,
                                               unsigned short* __restrict__ wt,
                                               int OC, int IC) {
  int n = OC * IC * 25;
  int idx = blockIdx.x * 256 + threadIdx.x;
  if (idx >= n) return;
  int t = idx / (OC * IC);
  int r = idx % (OC * IC);
  int o = r / IC, i = r % IC;
  wt[idx] = f2h(w[(o * IC + i) * 25 + t]);
}

// ----------------------------------------------- conv1a (CIN=1), direct fp32
// feat [64][120][64] fp32 -> A [64][120][64][64oc] fp16. grid (32, 64, 8).
__global__ __launch_bounds__(256) void k_conv1a(const float* __restrict__ in,
                                                const float* __restrict__ wgt,
                                                unsigned short* __restrict__ out) {
  __shared__ float tile[20 * 21];
  int tx = threadIdx.x & 15, ty = threadIdx.x >> 4;
  int tileX = (blockIdx.x & 3) * 16, tileY = (blockIdx.x >> 2) * 16;
  int b = blockIdx.y, ocb = blockIdx.z * 8;
  const float* inc = in + (size_t)b * 7680;
  for (int e = threadIdx.x; e < 400; e += 256) {
    int ly = e / 20, lx = e % 20;
    int gy = tileY - 2 + ly, gx = tileX - 2 + lx;
    float v = 0.f;
    if ((unsigned)gy < 120u && (unsigned)gx < 64u) v = inc[gy * 64 + gx];
    tile[ly * 21 + lx] = v;
  }
  __syncthreads();
  float tv[25];
#pragma unroll
  for (int dy = 0; dy < 5; ++dy)
#pragma unroll
    for (int dx = 0; dx < 5; ++dx)
      tv[dy * 5 + dx] = tile[(ty + dy) * 21 + tx + dx];
  float acc[8];
#pragma unroll
  for (int o = 0; o < 8; ++o) {
    const float* wo = wgt + (size_t)(ocb + o) * 25;
    float a = 0.f;
#pragma unroll
    for (int t = 0; t < 25; ++t) a = fmaf(tv[t], wo[t], a);
    acc[o] = a;
  }
  int oy = tileY + ty, ox = tileX + tx;
  if (oy < 120) {
    size_t base = (((size_t)b * 120 + oy) * 64 + ox) * 64 + ocb;
    ushort4 p0, p1;
    p0.x = f2h(acc[0]); p0.y = f2h(acc[1]); p0.z = f2h(acc[2]); p0.w = f2h(acc[3]);
    p1.x = f2h(acc[4]); p1.y = f2h(acc[5]); p1.z = f2h(acc[6]); p1.w = f2h(acc[7]);
    *(ushort4*)(out + base) = p0;
    *(ushort4*)(out + base + 4) = p1;
  }
}

// ---------------------------------------------- MFMA implicit-GEMM 5x5 conv
// NHWC fp16 in/out. Wave: 4 M-tiles (64 oc) x NT N-tiles (16 px each).
// LDS layout ic-chunk-major: lds[q][px][8ic] -> conflict-free b128 reads.
// grid (H/WGR, B, OC/64). Weights wt[t][oc][CIN] fp16.
template <int CIN, int H, int W, int NT, int OC>
__global__ __launch_bounds__(256) void k_convM(const unsigned short* __restrict__ in,
                                               const unsigned short* __restrict__ wt,
                                               unsigned short* __restrict__ out) {
  constexpr int XC = W / 16, RPW = NT / XC, WGR = 4 * RPW;
  constexpr int LW = W + 4, LR = WGR + 4, NPX = LR * LW;
  __shared__ unsigned short lds[4 * NPX * 8];
  int tid = threadIdx.x;
  int w = tid >> 6, lane = tid & 63, l15 = lane & 15, q = lane >> 4;
  int y0 = blockIdx.x * WGR, b = blockIdx.y, oc0 = blockIdx.z * 64;
  f32x4 acc[4][NT];
#pragma unroll
  for (int mt = 0; mt < 4; ++mt)
#pragma unroll
    for (int nt = 0; nt < NT; ++nt) acc[mt][nt] = 0.f;

  for (int icb = 0; icb < CIN / 32; ++icb) {
    __syncthreads();
    for (int e = tid; e < NPX * 4; e += 256) {
      int q4 = e & 3, px = e >> 2;
      int lr = px / LW, c = px % LW;
      int y = y0 - 2 + lr, x = c - 2;
      f16x8 v = (f16x8)0;
      if ((unsigned)y < (unsigned)H && (unsigned)x < (unsigned)W)
        v = *(const f16x8*)(in + (((size_t)b * H + y) * W + x) * CIN + icb * 32 + q4 * 8);
      *(f16x8*)&lds[((size_t)q4 * NPX + px) * 8] = v;
    }
    __syncthreads();
#pragma unroll
    for (int dy = 0; dy < 5; ++dy)
#pragma unroll
      for (int dx = 0; dx < 5; ++dx) {
        int t = dy * 5 + dx;
        f16x8 av[4];
#pragma unroll
        for (int mt = 0; mt < 4; ++mt)
          av[mt] = *(const f16x8*)(wt + ((size_t)(t * OC + oc0 + mt * 16 + l15) * CIN + icb * 32 + q * 8));
#pragma unroll
        for (int nt = 0; nt < NT; ++nt) {
          int lr = w * RPW + nt / XC + dy;
          int c = (nt % XC) * 16 + l15 + dx;
          f16x8 bv = *(const f16x8*)&lds[((size_t)q * NPX + lr * LW + c) * 8];
#pragma unroll
          for (int mt = 0; mt < 4; ++mt)
            acc[mt][nt] = __builtin_amdgcn_mfma_f32_16x16x32_f16(av[mt], bv, acc[mt][nt], 0, 0, 0);
        }
      }
  }
#pragma unroll
  for (int nt = 0; nt < NT; ++nt) {
    int y = y0 + w * RPW + nt / XC;
    if (y >= H) continue;
    int x = (nt % XC) * 16 + l15;
    size_t pbase = (((size_t)b * H + y) * W + x) * OC + oc0 + q * 4;
#pragma unroll
    for (int mt = 0; mt < 4; ++mt) {
      ushort4 pk;
      pk.x = f2h(acc[mt][nt][0]);
      pk.y = f2h(acc[mt][nt][1]);
      pk.z = f2h(acc[mt][nt][2]);
      pk.w = f2h(acc[mt][nt][3]);
      *(ushort4*)(out + pbase + mt * 16) = pk;
    }
  }
}

// --------------------------------------- BN stats stage 1: partial sums (f32)
__global__ __launch_bounds__(256) void k_bnstats2(const unsigned short* __restrict__ x,
                                                  float* __restrict__ acc,
                                                  int C, int P) {
  __shared__ float r1[256], r2[256];
  int ci = threadIdx.x & 63, pq = threadIdx.x >> 6;
  int c = blockIdx.y * 64 + ci;
  float s1 = 0.f, s2 = 0.f;
  size_t base = (size_t)blockIdx.x * P;
  for (int k = pq; k < P; k += 4) {
    float v = h2f(x[(base + k) * C + c]);
    s1 += v;
    s2 += v * v;
  }
  r1[pq * 64 + ci] = s1;
  r2[pq * 64 + ci] = s2;
  __syncthreads();
  if (pq == 0) {
    float t1 = r1[ci] + r1[64 + ci] + r1[128 + ci] + r1[192 + ci];
    float t2 = r2[ci] + r2[64 + ci] + r2[128 + ci] + r2[192 + ci];
    atomicAdd(&acc[c], t1);
    atomicAdd(&acc[C + c], t2);
  }
}

__global__ __launch_bounds__(256) void k_bnfin(const float* __restrict__ acc,
                                               float* __restrict__ stats,
                                               int C, float invN) {
  int c = threadIdx.x + blockIdx.x * 256;
  if (c >= C) return;
  float m = acc[c] * invN;
  float v = acc[C + c] * invN - m * m;
  stats[c] = m;
  stats[C + c] = rsqrtf(v + 1e-5f);
}

// ------------------------------------------- BN+ReLU in place (NHWC, x8 vec)
__global__ __launch_bounds__(256) void k_bnrelu1a(unsigned short* __restrict__ x,
                                                  const float* __restrict__ stats,
                                                  const float* __restrict__ g,
                                                  const float* __restrict__ be) {
  int idx = blockIdx.x * 256 + threadIdx.x;
  int c0 = (idx & 7) * 8;
  f16x8 v = *(const f16x8*)(x + (size_t)idx * 8);
  f16x8 r;
#pragma unroll
  for (int j = 0; j < 8; ++j) {
    int c = c0 + j;
    float f = (float)v[j];
    f = g[c] * ((f - stats[c]) * stats[64 + c]) + be[c];
    r[j] = (_Float16)(f > 0.f ? f : 0.f);
  }
  *(f16x8*)(x + (size_t)idx * 8) = r;
}

// --------------------------------------- BN+ReLU+maxpool2 NHWC (x8 vec)
template <int C, int H, int W>
__global__ __launch_bounds__(256) void k_brp(const unsigned short* __restrict__ x,
                                             unsigned short* __restrict__ y,
                                             const float* __restrict__ stats,
                                             const float* __restrict__ g,
                                             const float* __restrict__ be) {
  constexpr int OH = H / 2, OW = W / 2, CV = C / 8;
  int idx = blockIdx.x * 256 + threadIdx.x;   // [b][oy][ox][cv]
  int cv = idx % CV;
  int t = idx / CV;
  int ox = t % OW; t /= OW;
  int oy = t % OH;
  int b = t / OH;
  int c0 = cv * 8;
  const unsigned short* p = x + ((size_t)(b * H + oy * 2) * W + ox * 2) * C + c0;
  f16x8 v00 = *(const f16x8*)p;
  f16x8 v01 = *(const f16x8*)(p + C);
  f16x8 v10 = *(const f16x8*)(p + (size_t)W * C);
  f16x8 v11 = *(const f16x8*)(p + (size_t)W * C + C);
  f16x8 r;
#pragma unroll
  for (int j = 0; j < 8; ++j) {
    int c = c0 + j;
    float m = stats[c], iv = stats[C + c], gg = g[c], bb = be[c];
    float a0 = (float)v00[j], a1 = (float)v01[j], a2 = (float)v10[j], a3 = (float)v11[j];
    float m01 = a0 > a1 ? a0 : a1;
    float m23 = a2 > a3 ? a2 : a3;
    float mx = m01 > m23 ? m01 : m23;   // max before affine ok iff scale>0? no:
    // affine per-element then relu then max; scale sign matters -> do it right:
    float f0 = gg * ((a0 - m) * iv) + bb;
    float f1 = gg * ((a1 - m) * iv) + bb;
    float f2 = gg * ((a2 - m) * iv) + bb;
    float f3 = gg * ((a3 - m) * iv) + bb;
    f0 = f0 > 0.f ? f0 : 0.f;
    f1 = f1 > 0.f ? f1 : 0.f;
    f2 = f2 > 0.f ? f2 : 0.f;
    f3 = f3 > 0.f ? f3 : 0.f;
    float r01 = f0 > f1 ? f0 : f1;
    float r23 = f2 > f3 ? f2 : f3;
    (void)mx;
    r[j] = (_Float16)(r01 > r23 ? r01 : r23);
  }
  *(f16x8*)(y + (size_t)idx * 8) = r;
}

// ---- stage-3 BN+ReLU+pool + transpose into fc1 rows: inT[(64+c*120+s)*64+b]
__global__ __launch_bounds__(256) void k_brp3t(const unsigned short* __restrict__ x,
                                               float* __restrict__ inT,
                                               const float* __restrict__ stats,
                                               const float* __restrict__ g,
                                               const float* __restrict__ be) {
  __shared__ float tile[64 * 65];
  int s = blockIdx.x;
  int oy = s >> 3, ox = s & 7;
  int ci = threadIdx.x & 63, bq = threadIdx.x >> 6;
  for (int cs = 0; cs < 4; ++cs) {
    int c = cs * 64 + ci;
    float m = stats[c], iv = stats[256 + c], gg = g[c], bb = be[c];
    __syncthreads();
    for (int b = bq; b < 64; b += 4) {
      float mx = 0.f;
#pragma unroll
      for (int qq = 0; qq < 4; ++qq) {
        int yy = oy * 2 + (qq >> 1), xx = ox * 2 + (qq & 1);
        float v = h2f(x[((size_t)(b * 30 + yy) * 16 + xx) * 256 + c]);
        v = gg * ((v - m) * iv) + bb;
        v = v > 0.f ? v : 0.f;
        mx = v > mx ? v : mx;
      }
      tile[ci * 65 + b] = mx;
    }
    __syncthreads();
    for (int e = threadIdx.x; e < 4096; e += 256) {
      int cc = e >> 6, bb2 = e & 63;
      inT[(size_t)(64 + (cs * 64 + cc) * 120 + s) * 64 + bb2] = tile[cc * 65 + bb2];
    }
  }
}

// -------------------- q rows of fc inputs + zero fc1 accumulator + BN accums
__global__ __launch_bounds__(256) void k_qinit(const float* __restrict__ q,
                                               float* __restrict__ inT,
                                               float* __restrict__ in2T,
                                               float* __restrict__ in3T,
                                               float* __restrict__ z1pre,
                                               float* __restrict__ bnacc) {
  int idx = blockIdx.x * 256 + threadIdx.x;
  if (idx < 32000) z1pre[idx] = 0.f;
  else if (idx < 33024) bnacc[idx - 32000] = 0.f;
  if (idx >= 4096) return;
  int b = idx >> 6, i = idx & 63;
  float v = q[idx];
  inT[i * 64 + b] = v;
  in2T[i * 64 + b] = v;
  in3T[i * 64 + b] = v;
}

// ----------------------------------------------------------- fc1 (big GEMV)
__global__ __launch_bounds__(256) void k_fc1(const float* __restrict__ inT,
                                             const float* __restrict__ wgt,
                                             float* __restrict__ z1pre) {
  constexpr int IN = 30784;
  __shared__ float part[4][16][64];
  int ob = blockIdx.x * 16;
  int lane = threadIdx.x & 63, w = threadIdx.x >> 6;
  int i0 = blockIdx.y * 3848 + w * 962;
  int i1 = i0 + 962;
  float acc[16];
#pragma unroll
  for (int k = 0; k < 16; ++k) acc[k] = 0.f;
  for (int i = i0; i < i1; ++i) {
    float v = inT[(size_t)i * 64 + lane];
#pragma unroll
    for (int k = 0; k < 16; ++k) {
      int o = ob + k; o = o < 500 ? o : 499;
      acc[k] = fmaf(v, wgt[(size_t)o * IN + i], acc[k]);
    }
  }
#pragma unroll
  for (int k = 0; k < 16; ++k) part[w][k][lane] = acc[k];
  __syncthreads();
  int k4 = threadIdx.x >> 6;
  for (int kk = k4; kk < 16; kk += 4) {
    int o = ob + kk;
    if (o < 500) {
      float s = part[0][kk][lane] + part[1][kk][lane] + part[2][kk][lane] + part[3][kk][lane];
      atomicAdd(&z1pre[o * 64 + lane], s);
    }
  }
}

__global__ __launch_bounds__(256) void k_fc1ep(const float* __restrict__ z1pre,
                                               const float* __restrict__ bias,
                                               float* __restrict__ in2T) {
  int idx = blockIdx.x * 256 + threadIdx.x;
  if (idx >= 500 * 64) return;
  int o = idx >> 6;
  float v = z1pre[idx] + bias[o];
  in2T[idx + 64 * 64] = v > 0.f ? v : 0.f;
}

__global__ __launch_bounds__(256) void k_fc_small(const float* __restrict__ inT,
                                                  const float* __restrict__ wgt,
                                                  const float* __restrict__ bias,
                                                  float* __restrict__ out,
                                                  int IN, int mode) {
  __shared__ float part[4][64];
  int o = blockIdx.x;
  int lane = threadIdx.x & 63, w = threadIdx.x >> 6;
  float acc = 0.f;
  for (int i = w; i < IN; i += 4)
    acc = fmaf(inT[(size_t)i * 64 + lane], wgt[(size_t)o * IN + i], acc);
  part[w][lane] = acc;
  __syncthreads();
  if (threadIdx.x < 64) {
    float s = part[0][lane] + part[1][lane] + part[2][lane] + part[3][lane] + bias[o];
    if (mode == 0) {
      s = s > 0.f ? s : 0.f;
      out[(64 + o) * 64 + lane] = s;
    } else {
      out[lane * 2 + o] = s;
    }
  }
}

// ============================================================================
extern "C" void kernel_launch(void* const* d_in, const int* in_sizes, int n_in,
                              void* d_out, int out_size, void* d_ws, size_t ws_size,
                              hipStream_t stream) {
  const float* x      = (const float*)d_in[0];
  const float* qvec   = (const float*)d_in[1];
  const float* basis  = (const float*)d_in[2];
  const float* w1a    = (const float*)d_in[3];
  const float* g1a    = (const float*)d_in[5];
  const float* be1a   = (const float*)d_in[6];
  const float* w1b    = (const float*)d_in[7];
  const float* g1b    = (const float*)d_in[9];
  const float* be1b   = (const float*)d_in[10];
  const float* w2a    = (const float*)d_in[11];
  const float* g2a    = (const float*)d_in[13];
  const float* be2a   = (const float*)d_in[14];
  const float* w3a    = (const float*)d_in[15];
  const float* g3a    = (const float*)d_in[17];
  const float* be3a   = (const float*)d_in[18];
  const float* fc1w   = (const float*)d_in[19];
  const float* fc1b   = (const float*)d_in[20];
  const float* fc2w   = (const float*)d_in[21];
  const float* fc2b   = (const float*)d_in[22];
  const float* fc3w   = (const float*)d_in[23];
  const float* fc3b   = (const float*)d_in[24];
  float* out = (float*)d_out;

  char* base = (char*)d_ws;
  constexpr size_t ARENA = 62914560;
  char* arenaA = base;
  char* arenaB = base + ARENA;
  char* sm     = base + 2 * ARENA;

  float*          xd   = (float*)arenaA;
  unsigned short* A    = (unsigned short*)arenaA;  // pre1a NHWC [64][120][64][64]
  unsigned short* P1   = (unsigned short*)arenaA;  // [64][60][32][64]
  unsigned short* P2   = (unsigned short*)arenaA;  // [64][30][16][128]
  float*          inT  = (float*)arenaA;           // [30784][64] fp32

  float*          feat = (float*)arenaB;           // [64][120][64] fp32
  unsigned short* Bb   = (unsigned short*)arenaB;  // pre1b [64][120][64][64]
  unsigned short* C2   = (unsigned short*)arenaB;  // [64][60][32][128]
  unsigned short* D3   = (unsigned short*)arenaB;  // [64][30][16][256]

  float* in2T = (float*)sm;                    // 144,384 B
  float* in3T = (float*)(sm + 144384);         // 144,384 B
  float* z1p  = (float*)(sm + 288768);         // 128,000 B
  float* ACC  = (float*)(sm + 416768);         // 4,096 B
  float* S1A  = (float*)(sm + 420864);
  float* S1B  = (float*)(sm + 421376);
  float* S2A  = (float*)(sm + 421888);
  float* S3A  = (float*)(sm + 422912);
  unsigned short* WT1 = (unsigned short*)(sm + 424960);   // 204,800 B
  unsigned short* WT2 = (unsigned short*)(sm + 834560);   // 409,600 B
  unsigned short* WT3 = (unsigned short*)(sm + 1653760);  // 1,638,400 B

  k_qinit<<<130, 256, 0, stream>>>(qvec, inT, in2T, in3T, z1p, ACC);
  k_prepw<<<400, 256, 0, stream>>>(w1b, WT1, 64, 64);
  k_prepw<<<800, 256, 0, stream>>>(w2a, WT2, 128, 64);
  k_prepw<<<3200, 256, 0, stream>>>(w3a, WT3, 256, 128);

  k_dct<<<64 * 8, 256, 0, stream>>>(x, basis, xd);
  k_hist<<<4096, 256, 0, stream>>>(xd, feat);

  // conv1a (direct) -> A, BN stats + relu in place
  k_conv1a<<<dim3(32, 64, 8), 256, 0, stream>>>(feat, w1a, A);
  k_bnstats2<<<dim3(256, 1), 256, 0, stream>>>(A, ACC, 64, 1920);
  k_bnfin<<<1, 64, 0, stream>>>(ACC, S1A, 64, 1.f / 491520.f);
  k_bnrelu1a<<<15360, 256, 0, stream>>>(A, S1A, g1a, be1a);

  // conv1b (MFMA, 4Mx8N, WGR=8) -> Bb, BN stats, BN+relu+pool -> P1
  k_convM<64, 120, 64, 8, 64><<<dim3(15, 64, 1), 256, 0, stream>>>(A, WT1, Bb);
  k_bnstats2<<<dim3(256, 1), 256, 0, stream>>>(Bb, ACC + 128, 64, 1920);
  k_bnfin<<<1, 64, 0, stream>>>(ACC + 128, S1B, 64, 1.f / 491520.f);
  k_brp<64, 120, 64><<<3840, 256, 0, stream>>>(Bb, P1, S1B, g1b, be1b);

  // conv2a (MFMA, 4Mx8N, WGR=16) -> C2, stats, pool -> P2
  k_convM<64, 60, 32, 8, 128><<<dim3(4, 64, 2), 256, 0, stream>>>(P1, WT2, C2);
  k_bnstats2<<<dim3(64, 2), 256, 0, stream>>>(C2, ACC + 256, 128, 1920);
  k_bnfin<<<1, 128, 0, stream>>>(ACC + 256, S2A, 128, 1.f / 122880.f);
  k_brp<128, 60, 32><<<1920, 256, 0, stream>>>(C2, P2, S2A, g2a, be2a);

  // conv3a (MFMA, 4Mx4N, WGR=16) -> D3, stats, pool+transpose -> inT
  k_convM<128, 30, 16, 4, 256><<<dim3(2, 64, 4), 256, 0, stream>>>(P2, WT3, D3);
  k_bnstats2<<<dim3(16, 4), 256, 0, stream>>>(D3, ACC + 512, 256, 1920);
  k_bnfin<<<1, 256, 0, stream>>>(ACC + 512, S3A, 256, 1.f / 30720.f);
  k_qinit<<<130, 256, 0, stream>>>(qvec, inT, in2T, in3T, z1p, ACC);
  k_brp3t<<<120, 256, 0, stream>>>(D3, inT, S3A, g3a, be3a);

  // FC head
  k_fc1<<<dim3(32, 8), 256, 0, stream>>>(inT, fc1w, z1p);
  k_fc1ep<<<125, 256, 0, stream>>>(z1p, fc1b, in2T);
  k_fc_small<<<500, 256, 0, stream>>>(in2T, fc2w, fc2b, in3T, 564, 0);
  k_fc_small<<<2, 256, 0, stream>>>(in3T, fc3w, fc3b, out, 564, 1);
}

// Round 5
// 1570.018 us; speedup vs baseline: 3.5762x; 1.1511x over previous
//
#include <hip/hip_runtime.h>
#include <math.h>

// ============================================================================
// DoubleJpeg round 4: MFMA fc1 (batch-major fp16 activations, coalesced
// 16B weight loads) + contention-free counting histogram (no LDS atomics).
// Convs unchanged from round 3 (fp16 MFMA implicit GEMM).
// Arena A (62.91 MB): xd(fp32) -> pre1a A -> P1 -> P2 -> actT(fp16)
// Arena B (62.91 MB): feat(fp32) -> pre1b Bb -> C2 -> D3
// ============================================================================

typedef __attribute__((ext_vector_type(8))) _Float16 f16x8;
typedef __attribute__((ext_vector_type(4))) float f32x4;

#define GAMMA_F 1.0e6f

__device__ __forceinline__ unsigned short f2h(float f) {
  _Float16 h = (_Float16)f;
  union { _Float16 h; unsigned short u; } x; x.h = h; return x.u;
}
__device__ __forceinline__ float h2f(unsigned short u) {
  union { unsigned short u; _Float16 h; } x; x.u = u; return (float)x.h;
}

// ---------------------------------------------------------------- DCT kernel
__global__ __launch_bounds__(256) void k_dct(const float* __restrict__ x,
                                             const float* __restrict__ basis,
                                             float* __restrict__ xd) {
  __shared__ float bT[4096];
  __shared__ float pix[4][64];
  int tid = threadIdx.x;
  for (int e = tid; e < 4096; e += 256)
    bT[e] = basis[(e & 63) * 64 + (e >> 6)];
  __syncthreads();
  int w = tid >> 6, lane = tid & 63;
  int b = blockIdx.x >> 3;
  int br = ((blockIdx.x & 7) << 2) + w;
  const float* xb = x + (size_t)b * 65536;
  float* xdb = xd + (size_t)b * 65536;
  for (int bc = 0; bc < 32; ++bc) {
    __syncthreads();
    pix[w][lane] = xb[(br * 8 + (lane >> 3)) * 256 + bc * 8 + (lane & 7)];
    __syncthreads();
    float acc = 0.f;
#pragma unroll
    for (int p = 0; p < 64; ++p)
      acc = fmaf(bT[p * 64 + lane], pix[w][p], acc);
    xdb[lane * 1024 + br * 32 + bc] = acc;
  }
}

// ------------------------------- counting soft histogram (no atomics) -> feat
// grid 4096 (= b*64+c) x 256. Thread t: threshold j=t>>1, half h=t&1.
// cnt_j = sum_px sigmoid(1e6*(v - (j-60))) computed exactly (step + rare
// boundary correction). feat[b][j][c] = (cnt_j - cnt_{j+1})/1024.
__global__ __launch_bounds__(256) void k_hist(const float* __restrict__ xd,
                                              float* __restrict__ feat) {
  __shared__ float px[1024];
  __shared__ float part[242];
  __shared__ float tot[121];
  int tid = threadIdx.x;
  int bc = blockIdx.x;
  int b = bc >> 6, c = bc & 63;
  const float* p = xd + (size_t)bc * 1024;
  for (int e = tid; e < 1024; e += 256) px[e] = p[e];
  __syncthreads();
  if (tid < 242) {
    int j = tid >> 1;
    float bj = (float)(j - 60);
    int i0 = (tid & 1) * 512;
    float cnt = 0.f;
    for (int i = i0; i < i0 + 512; ++i) {
      float d = px[i] - bj;
      float step = d > 0.f ? 1.f : 0.f;
      cnt += step;
      if (fabsf(d) < 2e-5f)
        cnt += 1.f / (1.f + expf(-GAMMA_F * d)) - step;
    }
    part[tid] = cnt;
  }
  __syncthreads();
  if (tid < 121) tot[tid] = part[2 * tid] + part[2 * tid + 1];
  __syncthreads();
  if (tid < 120)
    feat[((size_t)b * 120 + tid) * 64 + c] = (tot[tid] - tot[tid + 1]) * (1.f / 1024.f);
}

// ------------------------------------------- weight prep: fp32 -> fp16
__global__ __launch_bounds__(256) void k_prepw(const float* __restrict__ w,
                                               unsigned short* __restrict__ wt,
                                               int OC, int IC) {
  int n = OC * IC * 25;
  int idx = blockIdx.x * 256 + threadIdx.x;
  if (idx >= n) return;
  int t = idx / (OC * IC);
  int r = idx % (OC * IC);
  int o = r / IC, i = r % IC;
  wt[idx] = f2h(w[(o * IC + i) * 25 + t]);
}

// ----------------------------------------------- conv1a (CIN=1), direct fp32
__global__ __launch_bounds__(256) void k_conv1a(const float* __restrict__ in,
                                                const float* __restrict__ wgt,
                                                unsigned short* __restrict__ out) {
  __shared__ float tile[20 * 21];
  int tx = threadIdx.x & 15, ty = threadIdx.x >> 4;
  int tileX = (blockIdx.x & 3) * 16, tileY = (blockIdx.x >> 2) * 16;
  int b = blockIdx.y, ocb = blockIdx.z * 8;
  const float* inc = in + (size_t)b * 7680;
  for (int e = threadIdx.x; e < 400; e += 256) {
    int ly = e / 20, lx = e % 20;
    int gy = tileY - 2 + ly, gx = tileX - 2 + lx;
    float v = 0.f;
    if ((unsigned)gy < 120u && (unsigned)gx < 64u) v = inc[gy * 64 + gx];
    tile[ly * 21 + lx] = v;
  }
  __syncthreads();
  float tv[25];
#pragma unroll
  for (int dy = 0; dy < 5; ++dy)
#pragma unroll
    for (int dx = 0; dx < 5; ++dx)
      tv[dy * 5 + dx] = tile[(ty + dy) * 21 + tx + dx];
  float acc[8];
#pragma unroll
  for (int o = 0; o < 8; ++o) {
    const float* wo = wgt + (size_t)(ocb + o) * 25;
    float a = 0.f;
#pragma unroll
    for (int t = 0; t < 25; ++t) a = fmaf(tv[t], wo[t], a);
    acc[o] = a;
  }
  int oy = tileY + ty, ox = tileX + tx;
  if (oy < 120) {
    size_t base = (((size_t)b * 120 + oy) * 64 + ox) * 64 + ocb;
    ushort4 p0, p1;
    p0.x = f2h(acc[0]); p0.y = f2h(acc[1]); p0.z = f2h(acc[2]); p0.w = f2h(acc[3]);
    p1.x = f2h(acc[4]); p1.y = f2h(acc[5]); p1.z = f2h(acc[6]); p1.w = f2h(acc[7]);
    *(ushort4*)(out + base) = p0;
    *(ushort4*)(out + base + 4) = p1;
  }
}

// ---------------------------------------------- MFMA implicit-GEMM 5x5 conv
template <int CIN, int H, int W, int NT, int OC>
__global__ __launch_bounds__(256) void k_convM(const unsigned short* __restrict__ in,
                                               const unsigned short* __restrict__ wt,
                                               unsigned short* __restrict__ out) {
  constexpr int XC = W / 16, RPW = NT / XC, WGR = 4 * RPW;
  constexpr int LW = W + 4, LR = WGR + 4, NPX = LR * LW;
  __shared__ unsigned short lds[4 * NPX * 8];
  int tid = threadIdx.x;
  int w = tid >> 6, lane = tid & 63, l15 = lane & 15, q = lane >> 4;
  int y0 = blockIdx.x * WGR, b = blockIdx.y, oc0 = blockIdx.z * 64;
  f32x4 acc[4][NT];
#pragma unroll
  for (int mt = 0; mt < 4; ++mt)
#pragma unroll
    for (int nt = 0; nt < NT; ++nt) acc[mt][nt] = 0.f;

  for (int icb = 0; icb < CIN / 32; ++icb) {
    __syncthreads();
    for (int e = tid; e < NPX * 4; e += 256) {
      int q4 = e & 3, px = e >> 2;
      int lr = px / LW, c = px % LW;
      int y = y0 - 2 + lr, x = c - 2;
      f16x8 v = (f16x8)0;
      if ((unsigned)y < (unsigned)H && (unsigned)x < (unsigned)W)
        v = *(const f16x8*)(in + (((size_t)b * H + y) * W + x) * CIN + icb * 32 + q4 * 8);
      *(f16x8*)&lds[((size_t)q4 * NPX + px) * 8] = v;
    }
    __syncthreads();
#pragma unroll
    for (int dy = 0; dy < 5; ++dy)
#pragma unroll
      for (int dx = 0; dx < 5; ++dx) {
        int t = dy * 5 + dx;
        f16x8 av[4];
#pragma unroll
        for (int mt = 0; mt < 4; ++mt)
          av[mt] = *(const f16x8*)(wt + ((size_t)(t * OC + oc0 + mt * 16 + l15) * CIN + icb * 32 + q * 8));
#pragma unroll
        for (int nt = 0; nt < NT; ++nt) {
          int lr = w * RPW + nt / XC + dy;
          int c = (nt % XC) * 16 + l15 + dx;
          f16x8 bv = *(const f16x8*)&lds[((size_t)q * NPX + lr * LW + c) * 8];
#pragma unroll
          for (int mt = 0; mt < 4; ++mt)
            acc[mt][nt] = __builtin_amdgcn_mfma_f32_16x16x32_f16(av[mt], bv, acc[mt][nt], 0, 0, 0);
        }
      }
  }
#pragma unroll
  for (int nt = 0; nt < NT; ++nt) {
    int y = y0 + w * RPW + nt / XC;
    if (y >= H) continue;
    int x = (nt % XC) * 16 + l15;
    size_t pbase = (((size_t)b * H + y) * W + x) * OC + oc0 + q * 4;
#pragma unroll
    for (int mt = 0; mt < 4; ++mt) {
      ushort4 pk;
      pk.x = f2h(acc[mt][nt][0]);
      pk.y = f2h(acc[mt][nt][1]);
      pk.z = f2h(acc[mt][nt][2]);
      pk.w = f2h(acc[mt][nt][3]);
      *(ushort4*)(out + pbase + mt * 16) = pk;
    }
  }
}

// --------------------------------------- BN stats stage 1: partial sums (f32)
__global__ __launch_bounds__(256) void k_bnstats2(const unsigned short* __restrict__ x,
                                                  float* __restrict__ acc,
                                                  int C, int P) {
  __shared__ float r1[256], r2[256];
  int ci = threadIdx.x & 63, pq = threadIdx.x >> 6;
  int c = blockIdx.y * 64 + ci;
  float s1 = 0.f, s2 = 0.f;
  size_t base = (size_t)blockIdx.x * P;
  for (int k = pq; k < P; k += 4) {
    float v = h2f(x[(base + k) * C + c]);
    s1 += v;
    s2 += v * v;
  }
  r1[pq * 64 + ci] = s1;
  r2[pq * 64 + ci] = s2;
  __syncthreads();
  if (pq == 0) {
    float t1 = r1[ci] + r1[64 + ci] + r1[128 + ci] + r1[192 + ci];
    float t2 = r2[ci] + r2[64 + ci] + r2[128 + ci] + r2[192 + ci];
    atomicAdd(&acc[c], t1);
    atomicAdd(&acc[C + c], t2);
  }
}

__global__ __launch_bounds__(256) void k_bnfin(const float* __restrict__ acc,
                                               float* __restrict__ stats,
                                               int C, float invN) {
  int c = threadIdx.x + blockIdx.x * 256;
  if (c >= C) return;
  float m = acc[c] * invN;
  float v = acc[C + c] * invN - m * m;
  stats[c] = m;
  stats[C + c] = rsqrtf(v + 1e-5f);
}

// ------------------------------------------- BN+ReLU in place (NHWC, x8 vec)
__global__ __launch_bounds__(256) void k_bnrelu1a(unsigned short* __restrict__ x,
                                                  const float* __restrict__ stats,
                                                  const float* __restrict__ g,
                                                  const float* __restrict__ be) {
  int idx = blockIdx.x * 256 + threadIdx.x;
  int c0 = (idx & 7) * 8;
  f16x8 v = *(const f16x8*)(x + (size_t)idx * 8);
  f16x8 r;
#pragma unroll
  for (int j = 0; j < 8; ++j) {
    int c = c0 + j;
    float f = (float)v[j];
    f = g[c] * ((f - stats[c]) * stats[64 + c]) + be[c];
    r[j] = (_Float16)(f > 0.f ? f : 0.f);
  }
  *(f16x8*)(x + (size_t)idx * 8) = r;
}

// --------------------------------------- BN+ReLU+maxpool2 NHWC (x8 vec)
template <int C, int H, int W>
__global__ __launch_bounds__(256) void k_brp(const unsigned short* __restrict__ x,
                                             unsigned short* __restrict__ y,
                                             const float* __restrict__ stats,
                                             const float* __restrict__ g,
                                             const float* __restrict__ be) {
  constexpr int OH = H / 2, OW = W / 2, CV = C / 8;
  int idx = blockIdx.x * 256 + threadIdx.x;   // [b][oy][ox][cv]
  int cv = idx % CV;
  int t = idx / CV;
  int ox = t % OW; t /= OW;
  int oy = t % OH;
  int b = t / OH;
  int c0 = cv * 8;
  const unsigned short* p = x + ((size_t)(b * H + oy * 2) * W + ox * 2) * C + c0;
  f16x8 v00 = *(const f16x8*)p;
  f16x8 v01 = *(const f16x8*)(p + C);
  f16x8 v10 = *(const f16x8*)(p + (size_t)W * C);
  f16x8 v11 = *(const f16x8*)(p + (size_t)W * C + C);
  f16x8 r;
#pragma unroll
  for (int j = 0; j < 8; ++j) {
    int c = c0 + j;
    float m = stats[c], iv = stats[C + c], gg = g[c], bb = be[c];
    float f0 = gg * (((float)v00[j] - m) * iv) + bb;
    float f1 = gg * (((float)v01[j] - m) * iv) + bb;
    float f2 = gg * (((float)v10[j] - m) * iv) + bb;
    float f3 = gg * (((float)v11[j] - m) * iv) + bb;
    f0 = f0 > 0.f ? f0 : 0.f;
    f1 = f1 > 0.f ? f1 : 0.f;
    f2 = f2 > 0.f ? f2 : 0.f;
    f3 = f3 > 0.f ? f3 : 0.f;
    float r01 = f0 > f1 ? f0 : f1;
    float r23 = f2 > f3 ? f2 : f3;
    r[j] = (_Float16)(r01 > r23 ? r01 : r23);
  }
  *(f16x8*)(y + (size_t)idx * 8) = r;
}

// ---- stage-3 BN+ReLU+pool + write into batch-major fc1 activations (fp16)
// D3 [64][30][16][256] -> actT[b][64 + c*120 + s]
__global__ __launch_bounds__(256) void k_brp3t(const unsigned short* __restrict__ x,
                                               unsigned short* __restrict__ actT,
                                               const float* __restrict__ stats,
                                               const float* __restrict__ g,
                                               const float* __restrict__ be) {
  __shared__ float tile[64 * 65];
  int s = blockIdx.x;
  int oy = s >> 3, ox = s & 7;
  int ci = threadIdx.x & 63, bq = threadIdx.x >> 6;
  for (int cs = 0; cs < 4; ++cs) {
    int c = cs * 64 + ci;
    float m = stats[c], iv = stats[256 + c], gg = g[c], bb = be[c];
    __syncthreads();
    for (int b = bq; b < 64; b += 4) {
      float mx = 0.f;
#pragma unroll
      for (int qq = 0; qq < 4; ++qq) {
        int yy = oy * 2 + (qq >> 1), xx = ox * 2 + (qq & 1);
        float v = h2f(x[((size_t)(b * 30 + yy) * 16 + xx) * 256 + c]);
        v = gg * ((v - m) * iv) + bb;
        v = v > 0.f ? v : 0.f;
        mx = v > mx ? v : mx;
      }
      tile[ci * 65 + b] = mx;
    }
    __syncthreads();
    for (int e = threadIdx.x; e < 4096; e += 256) {
      int cc = e >> 6, bb2 = e & 63;
      actT[(size_t)bb2 * 30784 + 64 + (cs * 64 + cc) * 120 + s] = f2h(tile[cc * 65 + bb2]);
    }
  }
}

// -------------------- q rows of fc inputs + zero fc1 accumulator + BN accums
__global__ __launch_bounds__(256) void k_qinit(const float* __restrict__ q,
                                               unsigned short* __restrict__ actT,
                                               float* __restrict__ in2T,
                                               float* __restrict__ in3T,
                                               float* __restrict__ z1pre,
                                               float* __restrict__ bnacc) {
  int idx = blockIdx.x * 256 + threadIdx.x;
  if (idx < 32000) z1pre[idx] = 0.f;
  else if (idx < 33024) bnacc[idx - 32000] = 0.f;
  if (idx >= 4096) return;
  int b = idx >> 6, i = idx & 63;
  float v = q[idx];
  actT[(size_t)b * 30784 + i] = f2h(v);
  in2T[i * 64 + b] = v;
  in3T[i * 64 + b] = v;
}

// --------------------------------------------------------- fc1 (MFMA GEMM)
// actT [64][30784] fp16, wgt [500][30784] fp32 (cvt in-kernel).
// grid (32 M-blocks, 8 K-splits) x 256; 4 waves = 4 K-stripes of same M-tile.
__global__ __launch_bounds__(256) void k_fc1m(const unsigned short* __restrict__ actT,
                                              const float* __restrict__ wgt,
                                              float* __restrict__ z1pre) {
  constexpr int IN = 30784;
  constexpr int KSTEPS = IN / 32;   // 962
  __shared__ float part[4][16][64];
  int tid = threadIdx.x;
  int w = tid >> 6, lane = tid & 63, l15 = lane & 15, q = lane >> 4;
  int ob = blockIdx.x * 16;
  int row = ob + l15; if (row > 499) row = 499;
  int kw = blockIdx.y * 4 + w;      // 0..31
  f32x4 acc[4];
#pragma unroll
  for (int nt = 0; nt < 4; ++nt) acc[nt] = 0.f;
  for (int s = kw; s < KSTEPS; s += 32) {
    int k0 = s * 32;
    const float4* wp = (const float4*)(wgt + (size_t)row * IN + k0 + q * 8);
    float4 wa = wp[0], wb = wp[1];
    f16x8 a;
    a[0] = (_Float16)wa.x; a[1] = (_Float16)wa.y;
    a[2] = (_Float16)wa.z; a[3] = (_Float16)wa.w;
    a[4] = (_Float16)wb.x; a[5] = (_Float16)wb.y;
    a[6] = (_Float16)wb.z; a[7] = (_Float16)wb.w;
#pragma unroll
    for (int nt = 0; nt < 4; ++nt) {
      f16x8 bv = *(const f16x8*)(actT + (size_t)(nt * 16 + l15) * IN + k0 + q * 8);
      acc[nt] = __builtin_amdgcn_mfma_f32_16x16x32_f16(a, bv, acc[nt], 0, 0, 0);
    }
  }
#pragma unroll
  for (int nt = 0; nt < 4; ++nt)
#pragma unroll
    for (int reg = 0; reg < 4; ++reg)
      part[w][q * 4 + reg][nt * 16 + l15] = acc[nt][reg];
  __syncthreads();
  for (int e = tid; e < 1024; e += 256) {
    int m = e >> 6, n = e & 63;
    float sum = part[0][m][n] + part[1][m][n] + part[2][m][n] + part[3][m][n];
    int o = ob + m;
    if (o < 500) atomicAdd(&z1pre[o * 64 + n], sum);
  }
}

__global__ __launch_bounds__(256) void k_fc1ep(const float* __restrict__ z1pre,
                                               const float* __restrict__ bias,
                                               float* __restrict__ in2T) {
  int idx = blockIdx.x * 256 + threadIdx.x;
  if (idx >= 500 * 64) return;
  int o = idx >> 6;
  float v = z1pre[idx] + bias[o];
  in2T[idx + 64 * 64] = v > 0.f ? v : 0.f;
}

__global__ __launch_bounds__(256) void k_fc_small(const float* __restrict__ inT,
                                                  const float* __restrict__ wgt,
                                                  const float* __restrict__ bias,
                                                  float* __restrict__ out,
                                                  int IN, int mode) {
  __shared__ float part[4][64];
  int o = blockIdx.x;
  int lane = threadIdx.x & 63, w = threadIdx.x >> 6;
  float acc = 0.f;
  for (int i = w; i < IN; i += 4)
    acc = fmaf(inT[(size_t)i * 64 + lane], wgt[(size_t)o * IN + i], acc);
  part[w][lane] = acc;
  __syncthreads();
  if (threadIdx.x < 64) {
    float s = part[0][lane] + part[1][lane] + part[2][lane] + part[3][lane] + bias[o];
    if (mode == 0) {
      s = s > 0.f ? s : 0.f;
      out[(64 + o) * 64 + lane] = s;
    } else {
      out[lane * 2 + o] = s;
    }
  }
}

// ============================================================================
extern "C" void kernel_launch(void* const* d_in, const int* in_sizes, int n_in,
                              void* d_out, int out_size, void* d_ws, size_t ws_size,
                              hipStream_t stream) {
  const float* x      = (const float*)d_in[0];
  const float* qvec   = (const float*)d_in[1];
  const float* basis  = (const float*)d_in[2];
  const float* w1a    = (const float*)d_in[3];
  const float* g1a    = (const float*)d_in[5];
  const float* be1a   = (const float*)d_in[6];
  const float* w1b    = (const float*)d_in[7];
  const float* g1b    = (const float*)d_in[9];
  const float* be1b   = (const float*)d_in[10];
  const float* w2a    = (const float*)d_in[11];
  const float* g2a    = (const float*)d_in[13];
  const float* be2a   = (const float*)d_in[14];
  const float* w3a    = (const float*)d_in[15];
  const float* g3a    = (const float*)d_in[17];
  const float* be3a   = (const float*)d_in[18];
  const float* fc1w   = (const float*)d_in[19];
  const float* fc1b   = (const float*)d_in[20];
  const float* fc2w   = (const float*)d_in[21];
  const float* fc2b   = (const float*)d_in[22];
  const float* fc3w   = (const float*)d_in[23];
  const float* fc3b   = (const float*)d_in[24];
  float* out = (float*)d_out;

  char* base = (char*)d_ws;
  constexpr size_t ARENA = 62914560;
  char* arenaA = base;
  char* arenaB = base + ARENA;
  char* sm     = base + 2 * ARENA;

  float*          xd   = (float*)arenaA;
  unsigned short* A    = (unsigned short*)arenaA;  // pre1a NHWC [64][120][64][64]
  unsigned short* P1   = (unsigned short*)arenaA;  // [64][60][32][64]
  unsigned short* P2   = (unsigned short*)arenaA;  // [64][30][16][128]
  unsigned short* actT = (unsigned short*)arenaA;  // [64][30784] fp16

  float*          feat = (float*)arenaB;           // [64][120][64] fp32
  unsigned short* Bb   = (unsigned short*)arenaB;  // pre1b [64][120][64][64]
  unsigned short* C2   = (unsigned short*)arenaB;  // [64][60][32][128]
  unsigned short* D3   = (unsigned short*)arenaB;  // [64][30][16][256]

  float* in2T = (float*)sm;                    // 144,384 B
  float* in3T = (float*)(sm + 144384);         // 144,384 B
  float* z1p  = (float*)(sm + 288768);         // 128,000 B
  float* ACC  = (float*)(sm + 416768);         // 4,096 B
  float* S1A  = (float*)(sm + 420864);
  float* S1B  = (float*)(sm + 421376);
  float* S2A  = (float*)(sm + 421888);
  float* S3A  = (float*)(sm + 422912);
  unsigned short* WT1 = (unsigned short*)(sm + 424960);   // 204,800 B
  unsigned short* WT2 = (unsigned short*)(sm + 834560);   // 409,600 B
  unsigned short* WT3 = (unsigned short*)(sm + 1653760);  // 1,638,400 B

  k_qinit<<<130, 256, 0, stream>>>(qvec, actT, in2T, in3T, z1p, ACC);
  k_prepw<<<400, 256, 0, stream>>>(w1b, WT1, 64, 64);
  k_prepw<<<800, 256, 0, stream>>>(w2a, WT2, 128, 64);
  k_prepw<<<3200, 256, 0, stream>>>(w3a, WT3, 256, 128);

  k_dct<<<64 * 8, 256, 0, stream>>>(x, basis, xd);
  k_hist<<<4096, 256, 0, stream>>>(xd, feat);

  // conv1a (direct) -> A, BN stats + relu in place
  k_conv1a<<<dim3(32, 64, 8), 256, 0, stream>>>(feat, w1a, A);
  k_bnstats2<<<dim3(256, 1), 256, 0, stream>>>(A, ACC, 64, 1920);
  k_bnfin<<<1, 64, 0, stream>>>(ACC, S1A, 64, 1.f / 491520.f);
  k_bnrelu1a<<<15360, 256, 0, stream>>>(A, S1A, g1a, be1a);

  // conv1b (MFMA, 4Mx8N, WGR=8) -> Bb, BN stats, BN+relu+pool -> P1
  k_convM<64, 120, 64, 8, 64><<<dim3(15, 64, 1), 256, 0, stream>>>(A, WT1, Bb);
  k_bnstats2<<<dim3(256, 1), 256, 0, stream>>>(Bb, ACC + 128, 64, 1920);
  k_bnfin<<<1, 64, 0, stream>>>(ACC + 128, S1B, 64, 1.f / 491520.f);
  k_brp<64, 120, 64><<<3840, 256, 0, stream>>>(Bb, P1, S1B, g1b, be1b);

  // conv2a (MFMA, 4Mx8N, WGR=16) -> C2, stats, pool -> P2
  k_convM<64, 60, 32, 8, 128><<<dim3(4, 64, 2), 256, 0, stream>>>(P1, WT2, C2);
  k_bnstats2<<<dim3(64, 2), 256, 0, stream>>>(C2, ACC + 256, 128, 1920);
  k_bnfin<<<1, 128, 0, stream>>>(ACC + 256, S2A, 128, 1.f / 122880.f);
  k_brp<128, 60, 32><<<1920, 256, 0, stream>>>(C2, P2, S2A, g2a, be2a);

  // conv3a (MFMA, 4Mx4N, WGR=16) -> D3, stats, pool+transpose -> actT
  k_convM<128, 30, 16, 4, 256><<<dim3(2, 64, 4), 256, 0, stream>>>(P2, WT3, D3);
  k_bnstats2<<<dim3(16, 4), 256, 0, stream>>>(D3, ACC + 512, 256, 1920);
  k_bnfin<<<1, 256, 0, stream>>>(ACC + 512, S3A, 256, 1.f / 30720.f);
  k_qinit<<<130, 256, 0, stream>>>(qvec, actT, in2T, in3T, z1p, ACC);
  k_brp3t<<<120, 256, 0, stream>>>(D3, actT, S3A, g3a, be3a);

  // FC head
  k_fc1m<<<dim3(32, 8), 256, 0, stream>>>(actT, fc1w, z1p);
  k_fc1ep<<<125, 256, 0, stream>>>(z1p, fc1b, in2T);
  k_fc_small<<<500, 256, 0, stream>>>(in2T, fc2w, fc2b, in3T, 564, 0);
  k_fc_small<<<2, 256, 0, stream>>>(in3T, fc3w, fc3b, out, 564, 1);
}

// Round 7
// 1099.414 us; speedup vs baseline: 5.1070x; 1.4280x over previous
//
#include <hip/hip_runtime.h>
#include <math.h>

// ============================================================================
// DoubleJpeg round 6: round 5 (de-spilled convM NT=4, weight prefetch,
// fused BN1a into conv1b staging, vectorized BN stats) + PREBN padding fix:
// BN affine is applied ONLY to in-bounds pixels; halo stays exactly 0
// (reference pads the normalized activations with zeros).
// Arena A (62.91 MB): xd(fp32) -> pre1a A(raw) -> P1 -> P2 -> actT(fp16)
// Arena B (62.91 MB): feat(fp32) -> pre1b Bb -> C2 -> D3
// ============================================================================

typedef __attribute__((ext_vector_type(8))) _Float16 f16x8;
typedef __attribute__((ext_vector_type(4))) float f32x4;

#define GAMMA_F 1.0e6f

__device__ __forceinline__ unsigned short f2h(float f) {
  _Float16 h = (_Float16)f;
  union { _Float16 h; unsigned short u; } x; x.h = h; return x.u;
}
__device__ __forceinline__ float h2f(unsigned short u) {
  union { unsigned short u; _Float16 h; } x; x.u = u; return (float)x.h;
}

// ---------------------------------------------------------------- DCT kernel
__global__ __launch_bounds__(256) void k_dct(const float* __restrict__ x,
                                             const float* __restrict__ basis,
                                             float* __restrict__ xd) {
  __shared__ float bT[4096];
  __shared__ float pix[4][64];
  int tid = threadIdx.x;
  for (int e = tid; e < 4096; e += 256)
    bT[e] = basis[(e & 63) * 64 + (e >> 6)];
  __syncthreads();
  int w = tid >> 6, lane = tid & 63;
  int b = blockIdx.x >> 3;
  int br = ((blockIdx.x & 7) << 2) + w;
  const float* xb = x + (size_t)b * 65536;
  float* xdb = xd + (size_t)b * 65536;
  for (int bc = 0; bc < 32; ++bc) {
    __syncthreads();
    pix[w][lane] = xb[(br * 8 + (lane >> 3)) * 256 + bc * 8 + (lane & 7)];
    __syncthreads();
    float acc = 0.f;
#pragma unroll
    for (int p = 0; p < 64; ++p)
      acc = fmaf(bT[p * 64 + lane], pix[w][p], acc);
    xdb[lane * 1024 + br * 32 + bc] = acc;
  }
}

// ------------------------------- counting soft histogram (no atomics) -> feat
__global__ __launch_bounds__(256) void k_hist(const float* __restrict__ xd,
                                              float* __restrict__ feat) {
  __shared__ float px[1024];
  __shared__ float part[242];
  __shared__ float tot[121];
  int tid = threadIdx.x;
  int bc = blockIdx.x;
  int b = bc >> 6, c = bc & 63;
  const float* p = xd + (size_t)bc * 1024;
  for (int e = tid; e < 1024; e += 256) px[e] = p[e];
  __syncthreads();
  if (tid < 242) {
    int j = tid >> 1;
    float bj = (float)(j - 60);
    int i0 = (tid & 1) * 512;
    float cnt = 0.f;
    for (int i = i0; i < i0 + 512; ++i) {
      float d = px[i] - bj;
      float step = d > 0.f ? 1.f : 0.f;
      cnt += step;
      if (fabsf(d) < 2e-5f)
        cnt += 1.f / (1.f + expf(-GAMMA_F * d)) - step;
    }
    part[tid] = cnt;
  }
  __syncthreads();
  if (tid < 121) tot[tid] = part[2 * tid] + part[2 * tid + 1];
  __syncthreads();
  if (tid < 120)
    feat[((size_t)b * 120 + tid) * 64 + c] = (tot[tid] - tot[tid + 1]) * (1.f / 1024.f);
}

// ------------------------------------------- weight prep: fp32 -> fp16
__global__ __launch_bounds__(256) void k_prepw(const float* __restrict__ w,
                                               unsigned short* __restrict__ wt,
                                               int OC, int IC) {
  int n = OC * IC * 25;
  int idx = blockIdx.x * 256 + threadIdx.x;
  if (idx >= n) return;
  int t = idx / (OC * IC);
  int r = idx % (OC * IC);
  int o = r / IC, i = r % IC;
  wt[idx] = f2h(w[(o * IC + i) * 25 + t]);
}

// ----------------------------------------------- conv1a (CIN=1), direct fp32
__global__ __launch_bounds__(256) void k_conv1a(const float* __restrict__ in,
                                                const float* __restrict__ wgt,
                                                unsigned short* __restrict__ out) {
  __shared__ float tile[20 * 21];
  int tx = threadIdx.x & 15, ty = threadIdx.x >> 4;
  int tileX = (blockIdx.x & 3) * 16, tileY = (blockIdx.x >> 2) * 16;
  int b = blockIdx.y, ocb = blockIdx.z * 8;
  const float* inc = in + (size_t)b * 7680;
  for (int e = threadIdx.x; e < 400; e += 256) {
    int ly = e / 20, lx = e % 20;
    int gy = tileY - 2 + ly, gx = tileX - 2 + lx;
    float v = 0.f;
    if ((unsigned)gy < 120u && (unsigned)gx < 64u) v = inc[gy * 64 + gx];
    tile[ly * 21 + lx] = v;
  }
  __syncthreads();
  float tv[25];
#pragma unroll
  for (int dy = 0; dy < 5; ++dy)
#pragma unroll
    for (int dx = 0; dx < 5; ++dx)
      tv[dy * 5 + dx] = tile[(ty + dy) * 21 + tx + dx];
  float acc[8];
#pragma unroll
  for (int o = 0; o < 8; ++o) {
    const float* wo = wgt + (size_t)(ocb + o) * 25;
    float a = 0.f;
#pragma unroll
    for (int t = 0; t < 25; ++t) a = fmaf(tv[t], wo[t], a);
    acc[o] = a;
  }
  int oy = tileY + ty, ox = tileX + tx;
  if (oy < 120) {
    size_t base = (((size_t)b * 120 + oy) * 64 + ox) * 64 + ocb;
    ushort4 p0, p1;
    p0.x = f2h(acc[0]); p0.y = f2h(acc[1]); p0.z = f2h(acc[2]); p0.w = f2h(acc[3]);
    p1.x = f2h(acc[4]); p1.y = f2h(acc[5]); p1.z = f2h(acc[6]); p1.w = f2h(acc[7]);
    *(ushort4*)(out + base) = p0;
    *(ushort4*)(out + base + 4) = p1;
  }
}

// ---------------------------------------------- MFMA implicit-GEMM 5x5 conv
// NHWC fp16. Wave: 4 M-tiles (64 oc) x 4 N-tiles (16 px each).
// PREBN: apply BN(stats pst)+ReLU to IN-BOUNDS input during LDS staging;
// halo pixels stay exactly 0 (reference pads post-BN activations with 0).
// Weight frags prefetched one tap ahead (global->reg pipeline).
template <int CIN, int H, int W, int NT, int OC, bool PREBN>
__global__ __launch_bounds__(256, 3) void k_convM(const unsigned short* __restrict__ in,
                                                  const unsigned short* __restrict__ wt,
                                                  unsigned short* __restrict__ out,
                                                  const float* __restrict__ pst,
                                                  const float* __restrict__ pg,
                                                  const float* __restrict__ pbe) {
  constexpr int XC = W / 16, RPW = NT / XC, WGR = 4 * RPW;
  constexpr int LW = W + 4, LR = WGR + 4, NPX = LR * LW;
  __shared__ unsigned short lds[4 * NPX * 8];
  int tid = threadIdx.x;
  int w = tid >> 6, lane = tid & 63, l15 = lane & 15, q = lane >> 4;
  int q4 = tid & 3;
  int y0 = blockIdx.x * WGR, b = blockIdx.y, oc0 = blockIdx.z * 64;
  f32x4 acc[4][NT];
#pragma unroll
  for (int mt = 0; mt < 4; ++mt)
#pragma unroll
    for (int nt = 0; nt < NT; ++nt) acc[mt][nt] = 0.f;

  for (int icb = 0; icb < CIN / 32; ++icb) {
    float s8[8], a8[8];
    if (PREBN) {
      int cb = icb * 32 + q4 * 8;
#pragma unroll
      for (int j = 0; j < 8; ++j) {
        float m = pst[cb + j], iv = pst[CIN + cb + j];
        s8[j] = pg[cb + j] * iv;
        a8[j] = pbe[cb + j] - m * s8[j];
      }
    }
    __syncthreads();
    for (int e = tid; e < NPX * 4; e += 256) {
      int px = e >> 2;                 // e&3 == q4 (invariant per thread)
      int lr = px / LW, c = px % LW;
      int y = y0 - 2 + lr, x = c - 2;
      f16x8 v = (f16x8)0;
      if ((unsigned)y < (unsigned)H && (unsigned)x < (unsigned)W) {
        v = *(const f16x8*)(in + (((size_t)b * H + y) * W + x) * CIN + icb * 32 + q4 * 8);
        if (PREBN) {
#pragma unroll
          for (int j = 0; j < 8; ++j) {
            float f = fmaf((float)v[j], s8[j], a8[j]);
            v[j] = (_Float16)(f > 0.f ? f : 0.f);
          }
        }
      }
      *(f16x8*)&lds[((size_t)q4 * NPX + px) * 8] = v;
    }
    __syncthreads();
    const unsigned short* wp0 = wt + (size_t)(oc0 + l15) * CIN + icb * 32 + q * 8;
    f16x8 avn[4];
#pragma unroll
    for (int mt = 0; mt < 4; ++mt)
      avn[mt] = *(const f16x8*)(wp0 + (size_t)(mt * 16) * CIN);
#pragma unroll
    for (int t = 0; t < 25; ++t) {
      int dy = t / 5, dx = t % 5;
      f16x8 avc[4];
#pragma unroll
      for (int mt = 0; mt < 4; ++mt) avc[mt] = avn[mt];
      if (t < 24) {
#pragma unroll
        for (int mt = 0; mt < 4; ++mt)
          avn[mt] = *(const f16x8*)(wp0 + (size_t)((t + 1) * OC + mt * 16) * CIN);
      }
#pragma unroll
      for (int nt = 0; nt < NT; ++nt) {
        int lr = w * RPW + nt / XC + dy;
        int c = (nt % XC) * 16 + l15 + dx;
        f16x8 bv = *(const f16x8*)&lds[((size_t)q * NPX + lr * LW + c) * 8];
#pragma unroll
        for (int mt = 0; mt < 4; ++mt)
          acc[mt][nt] = __builtin_amdgcn_mfma_f32_16x16x32_f16(avc[mt], bv, acc[mt][nt], 0, 0, 0);
      }
    }
  }
#pragma unroll
  for (int nt = 0; nt < NT; ++nt) {
    int y = y0 + w * RPW + nt / XC;
    if (y >= H) continue;
    int x = (nt % XC) * 16 + l15;
    size_t pbase = (((size_t)b * H + y) * W + x) * OC + oc0 + q * 4;
#pragma unroll
    for (int mt = 0; mt < 4; ++mt) {
      ushort4 pk;
      pk.x = f2h(acc[mt][nt][0]);
      pk.y = f2h(acc[mt][nt][1]);
      pk.z = f2h(acc[mt][nt][2]);
      pk.w = f2h(acc[mt][nt][3]);
      *(ushort4*)(out + pbase + mt * 16) = pk;
    }
  }
}

// ------------------- BN stats, vectorized f16x8 (fully coalesced 1KB/wave)
template <int C>
__global__ __launch_bounds__(256) void k_bnstatsv(const unsigned short* __restrict__ x,
                                                  float* __restrict__ acc,
                                                  int nIter) {
  constexpr int CV = C / 8, KPB = 256 / CV;
  __shared__ float r1[256][8], r2[256][8];
  int tid = threadIdx.x;
  int cv = tid % CV, kq = tid / CV;
  size_t row0 = (size_t)blockIdx.x * (KPB * nIter) + kq;
  const unsigned short* p = x + row0 * C + cv * 8;
  float s1[8], s2[8];
#pragma unroll
  for (int j = 0; j < 8; ++j) { s1[j] = 0.f; s2[j] = 0.f; }
  for (int it = 0; it < nIter; ++it) {
    f16x8 v = *(const f16x8*)(p + (size_t)it * KPB * C);
#pragma unroll
    for (int j = 0; j < 8; ++j) {
      float f = (float)v[j];
      s1[j] += f;
      s2[j] += f * f;
    }
  }
#pragma unroll
  for (int j = 0; j < 8; ++j) { r1[tid][j] = s1[j]; r2[tid][j] = s2[j]; }
  __syncthreads();
  if (tid < C) {
    int cv0 = tid >> 3, e = tid & 7;
    float t1 = 0.f, t2 = 0.f;
    for (int k = 0; k < KPB; ++k) {
      t1 += r1[k * CV + cv0][e];
      t2 += r2[k * CV + cv0][e];
    }
    atomicAdd(&acc[tid], t1);
    atomicAdd(&acc[C + tid], t2);
  }
}

__global__ __launch_bounds__(256) void k_bnfin(const float* __restrict__ acc,
                                               float* __restrict__ stats,
                                               int C, float invN) {
  int c = threadIdx.x + blockIdx.x * 256;
  if (c >= C) return;
  float m = acc[c] * invN;
  float v = acc[C + c] * invN - m * m;
  stats[c] = m;
  stats[C + c] = rsqrtf(v + 1e-5f);
}

// --------------------------------------- BN+ReLU+maxpool2 NHWC (x8 vec)
template <int C, int H, int W>
__global__ __launch_bounds__(256) void k_brp(const unsigned short* __restrict__ x,
                                             unsigned short* __restrict__ y,
                                             const float* __restrict__ stats,
                                             const float* __restrict__ g,
                                             const float* __restrict__ be) {
  constexpr int OH = H / 2, OW = W / 2, CV = C / 8;
  int idx = blockIdx.x * 256 + threadIdx.x;   // [b][oy][ox][cv]
  int cv = idx % CV;
  int t = idx / CV;
  int ox = t % OW; t /= OW;
  int oy = t % OH;
  int b = t / OH;
  int c0 = cv * 8;
  const unsigned short* p = x + ((size_t)(b * H + oy * 2) * W + ox * 2) * C + c0;
  f16x8 v00 = *(const f16x8*)p;
  f16x8 v01 = *(const f16x8*)(p + C);
  f16x8 v10 = *(const f16x8*)(p + (size_t)W * C);
  f16x8 v11 = *(const f16x8*)(p + (size_t)W * C + C);
  f16x8 r;
#pragma unroll
  for (int j = 0; j < 8; ++j) {
    int c = c0 + j;
    float m = stats[c], iv = stats[C + c], gg = g[c], bb = be[c];
    float f0 = gg * (((float)v00[j] - m) * iv) + bb;
    float f1 = gg * (((float)v01[j] - m) * iv) + bb;
    float f2 = gg * (((float)v10[j] - m) * iv) + bb;
    float f3 = gg * (((float)v11[j] - m) * iv) + bb;
    f0 = f0 > 0.f ? f0 : 0.f;
    f1 = f1 > 0.f ? f1 : 0.f;
    f2 = f2 > 0.f ? f2 : 0.f;
    f3 = f3 > 0.f ? f3 : 0.f;
    float r01 = f0 > f1 ? f0 : f1;
    float r23 = f2 > f3 ? f2 : f3;
    r[j] = (_Float16)(r01 > r23 ? r01 : r23);
  }
  *(f16x8*)(y + (size_t)idx * 8) = r;
}

// ---- stage-3 BN+ReLU+pool + write into batch-major fc1 activations (fp16)
__global__ __launch_bounds__(256) void k_brp3t(const unsigned short* __restrict__ x,
                                               unsigned short* __restrict__ actT,
                                               const float* __restrict__ stats,
                                               const float* __restrict__ g,
                                               const float* __restrict__ be) {
  __shared__ float tile[64 * 65];
  int s = blockIdx.x;
  int oy = s >> 3, ox = s & 7;
  int ci = threadIdx.x & 63, bq = threadIdx.x >> 6;
  for (int cs = 0; cs < 4; ++cs) {
    int c = cs * 64 + ci;
    float m = stats[c], iv = stats[256 + c], gg = g[c], bb = be[c];
    __syncthreads();
    for (int b = bq; b < 64; b += 4) {
      float mx = 0.f;
#pragma unroll
      for (int qq = 0; qq < 4; ++qq) {
        int yy = oy * 2 + (qq >> 1), xx = ox * 2 + (qq & 1);
        float v = h2f(x[((size_t)(b * 30 + yy) * 16 + xx) * 256 + c]);
        v = gg * ((v - m) * iv) + bb;
        v = v > 0.f ? v : 0.f;
        mx = v > mx ? v : mx;
      }
      tile[ci * 65 + b] = mx;
    }
    __syncthreads();
    for (int e = threadIdx.x; e < 4096; e += 256) {
      int cc = e >> 6, bb2 = e & 63;
      actT[(size_t)bb2 * 30784 + 64 + (cs * 64 + cc) * 120 + s] = f2h(tile[cc * 65 + bb2]);
    }
  }
}

// -------------------- q rows of fc inputs + zero fc1 accumulator + BN accums
__global__ __launch_bounds__(256) void k_qinit(const float* __restrict__ q,
                                               unsigned short* __restrict__ actT,
                                               float* __restrict__ in2T,
                                               float* __restrict__ in3T,
                                               float* __restrict__ z1pre,
                                               float* __restrict__ bnacc) {
  int idx = blockIdx.x * 256 + threadIdx.x;
  if (idx < 32000) z1pre[idx] = 0.f;
  else if (idx < 33024) bnacc[idx - 32000] = 0.f;
  if (idx >= 4096) return;
  int b = idx >> 6, i = idx & 63;
  float v = q[idx];
  actT[(size_t)b * 30784 + i] = f2h(v);
  in2T[i * 64 + b] = v;
  in3T[i * 64 + b] = v;
}

// --------------------------------------------------------- fc1 (MFMA GEMM)
__global__ __launch_bounds__(256) void k_fc1m(const unsigned short* __restrict__ actT,
                                              const float* __restrict__ wgt,
                                              float* __restrict__ z1pre) {
  constexpr int IN = 30784;
  constexpr int KSTEPS = IN / 32;   // 962
  __shared__ float part[4][16][64];
  int tid = threadIdx.x;
  int w = tid >> 6, lane = tid & 63, l15 = lane & 15, q = lane >> 4;
  int ob = blockIdx.x * 16;
  int row = ob + l15; if (row > 499) row = 499;
  int kw = blockIdx.y * 4 + w;      // 0..31
  f32x4 acc[4];
#pragma unroll
  for (int nt = 0; nt < 4; ++nt) acc[nt] = 0.f;
  for (int s = kw; s < KSTEPS; s += 32) {
    int k0 = s * 32;
    const float4* wp = (const float4*)(wgt + (size_t)row * IN + k0 + q * 8);
    float4 wa = wp[0], wb = wp[1];
    f16x8 a;
    a[0] = (_Float16)wa.x; a[1] = (_Float16)wa.y;
    a[2] = (_Float16)wa.z; a[3] = (_Float16)wa.w;
    a[4] = (_Float16)wb.x; a[5] = (_Float16)wb.y;
    a[6] = (_Float16)wb.z; a[7] = (_Float16)wb.w;
#pragma unroll
    for (int nt = 0; nt < 4; ++nt) {
      f16x8 bv = *(const f16x8*)(actT + (size_t)(nt * 16 + l15) * IN + k0 + q * 8);
      acc[nt] = __builtin_amdgcn_mfma_f32_16x16x32_f16(a, bv, acc[nt], 0, 0, 0);
    }
  }
#pragma unroll
  for (int nt = 0; nt < 4; ++nt)
#pragma unroll
    for (int reg = 0; reg < 4; ++reg)
      part[w][q * 4 + reg][nt * 16 + l15] = acc[nt][reg];
  __syncthreads();
  for (int e = tid; e < 1024; e += 256) {
    int m = e >> 6, n = e & 63;
    float sum = part[0][m][n] + part[1][m][n] + part[2][m][n] + part[3][m][n];
    int o = ob + m;
    if (o < 500) atomicAdd(&z1pre[o * 64 + n], sum);
  }
}

__global__ __launch_bounds__(256) void k_fc1ep(const float* __restrict__ z1pre,
                                               const float* __restrict__ bias,
                                               float* __restrict__ in2T) {
  int idx = blockIdx.x * 256 + threadIdx.x;
  if (idx >= 500 * 64) return;
  int o = idx >> 6;
  float v = z1pre[idx] + bias[o];
  in2T[idx + 64 * 64] = v > 0.f ? v : 0.f;
}

__global__ __launch_bounds__(256) void k_fc_small(const float* __restrict__ inT,
                                                  const float* __restrict__ wgt,
                                                  const float* __restrict__ bias,
                                                  float* __restrict__ out,
                                                  int IN, int mode) {
  __shared__ float part[4][64];
  int o = blockIdx.x;
  int lane = threadIdx.x & 63, w = threadIdx.x >> 6;
  float acc = 0.f;
  for (int i = w; i < IN; i += 4)
    acc = fmaf(inT[(size_t)i * 64 + lane], wgt[(size_t)o * IN + i], acc);
  part[w][lane] = acc;
  __syncthreads();
  if (threadIdx.x < 64) {
    float s = part[0][lane] + part[1][lane] + part[2][lane] + part[3][lane] + bias[o];
    if (mode == 0) {
      s = s > 0.f ? s : 0.f;
      out[(64 + o) * 64 + lane] = s;
    } else {
      out[lane * 2 + o] = s;
    }
  }
}

// ============================================================================
extern "C" void kernel_launch(void* const* d_in, const int* in_sizes, int n_in,
                              void* d_out, int out_size, void* d_ws, size_t ws_size,
                              hipStream_t stream) {
  const float* x      = (const float*)d_in[0];
  const float* qvec   = (const float*)d_in[1];
  const float* basis  = (const float*)d_in[2];
  const float* w1a    = (const float*)d_in[3];
  const float* g1a    = (const float*)d_in[5];
  const float* be1a   = (const float*)d_in[6];
  const float* w1b    = (const float*)d_in[7];
  const float* g1b    = (const float*)d_in[9];
  const float* be1b   = (const float*)d_in[10];
  const float* w2a    = (const float*)d_in[11];
  const float* g2a    = (const float*)d_in[13];
  const float* be2a   = (const float*)d_in[14];
  const float* w3a    = (const float*)d_in[15];
  const float* g3a    = (const float*)d_in[17];
  const float* be3a   = (const float*)d_in[18];
  const float* fc1w   = (const float*)d_in[19];
  const float* fc1b   = (const float*)d_in[20];
  const float* fc2w   = (const float*)d_in[21];
  const float* fc2b   = (const float*)d_in[22];
  const float* fc3w   = (const float*)d_in[23];
  const float* fc3b   = (const float*)d_in[24];
  float* out = (float*)d_out;

  char* base = (char*)d_ws;
  constexpr size_t ARENA = 62914560;
  char* arenaA = base;
  char* arenaB = base + ARENA;
  char* sm     = base + 2 * ARENA;

  float*          xd   = (float*)arenaA;
  unsigned short* A    = (unsigned short*)arenaA;  // pre1a NHWC [64][120][64][64] (raw)
  unsigned short* P1   = (unsigned short*)arenaA;  // [64][60][32][64]
  unsigned short* P2   = (unsigned short*)arenaA;  // [64][30][16][128]
  unsigned short* actT = (unsigned short*)arenaA;  // [64][30784] fp16

  float*          feat = (float*)arenaB;           // [64][120][64] fp32
  unsigned short* Bb   = (unsigned short*)arenaB;  // pre1b [64][120][64][64]
  unsigned short* C2   = (unsigned short*)arenaB;  // [64][60][32][128]
  unsigned short* D3   = (unsigned short*)arenaB;  // [64][30][16][256]

  float* in2T = (float*)sm;                    // 144,384 B
  float* in3T = (float*)(sm + 144384);         // 144,384 B
  float* z1p  = (float*)(sm + 288768);         // 128,000 B
  float* ACC  = (float*)(sm + 416768);         // 4,096 B
  float* S1A  = (float*)(sm + 420864);
  float* S1B  = (float*)(sm + 421376);
  float* S2A  = (float*)(sm + 421888);
  float* S3A  = (float*)(sm + 422912);
  unsigned short* WT1 = (unsigned short*)(sm + 424960);   // 204,800 B
  unsigned short* WT2 = (unsigned short*)(sm + 834560);   // 409,600 B
  unsigned short* WT3 = (unsigned short*)(sm + 1653760);  // 1,638,400 B

  k_qinit<<<130, 256, 0, stream>>>(qvec, actT, in2T, in3T, z1p, ACC);
  k_prepw<<<400, 256, 0, stream>>>(w1b, WT1, 64, 64);
  k_prepw<<<800, 256, 0, stream>>>(w2a, WT2, 128, 64);
  k_prepw<<<3200, 256, 0, stream>>>(w3a, WT3, 256, 128);

  k_dct<<<64 * 8, 256, 0, stream>>>(x, basis, xd);
  k_hist<<<4096, 256, 0, stream>>>(xd, feat);

  // conv1a (direct) -> A (raw pre-activations), stats over A
  k_conv1a<<<dim3(32, 64, 8), 256, 0, stream>>>(feat, w1a, A);
  k_bnstatsv<64><<<240, 256, 0, stream>>>(A, ACC, 64);
  k_bnfin<<<1, 64, 0, stream>>>(ACC, S1A, 64, 1.f / 491520.f);

  // conv1b (MFMA, PREBN applies BN1a+ReLU during staging) -> Bb
  k_convM<64, 120, 64, 4, 64, true><<<dim3(30, 64, 1), 256, 0, stream>>>(
      A, WT1, Bb, S1A, g1a, be1a);
  k_bnstatsv<64><<<240, 256, 0, stream>>>(Bb, ACC + 128, 64);
  k_bnfin<<<1, 64, 0, stream>>>(ACC + 128, S1B, 64, 1.f / 491520.f);
  k_brp<64, 120, 64><<<3840, 256, 0, stream>>>(Bb, P1, S1B, g1b, be1b);

  // conv2a -> C2, stats, pool -> P2
  k_convM<64, 60, 32, 4, 128, false><<<dim3(8, 64, 2), 256, 0, stream>>>(
      P1, WT2, C2, S1A, g1a, be1a);
  k_bnstatsv<128><<<240, 256, 0, stream>>>(C2, ACC + 256, 32);
  k_bnfin<<<1, 128, 0, stream>>>(ACC + 256, S2A, 128, 1.f / 122880.f);
  k_brp<128, 60, 32><<<1920, 256, 0, stream>>>(C2, P2, S2A, g2a, be2a);

  // conv3a -> D3, stats, pool+transpose -> actT
  k_convM<128, 30, 16, 4, 256, false><<<dim3(2, 64, 4), 256, 0, stream>>>(
      P2, WT3, D3, S1A, g1a, be1a);
  k_bnstatsv<256><<<240, 256, 0, stream>>>(D3, ACC + 512, 16);
  k_bnfin<<<1, 256, 0, stream>>>(ACC + 512, S3A, 256, 1.f / 30720.f);
  k_qinit<<<130, 256, 0, stream>>>(qvec, actT, in2T, in3T, z1p, ACC);
  k_brp3t<<<120, 256, 0, stream>>>(D3, actT, S3A, g3a, be3a);

  // FC head
  k_fc1m<<<dim3(32, 8), 256, 0, stream>>>(actT, fc1w, z1p);
  k_fc1ep<<<125, 256, 0, stream>>>(z1p, fc1b, in2T);
  k_fc_small<<<500, 256, 0, stream>>>(in2T, fc2w, fc2b, in3T, 564, 0);
  k_fc_small<<<2, 256, 0, stream>>>(in3T, fc3w, fc3b, out, 564, 1);
}